// Round 7
// baseline (176.107 us; speedup 1.0000x reference)
//
#include <hip/hip_runtime.h>
#include <math.h>

typedef __attribute__((ext_vector_type(8))) short short8;
typedef __attribute__((ext_vector_type(4))) float f32x4;
typedef __attribute__((ext_vector_type(4))) unsigned short us4v;

__device__ __forceinline__ unsigned short f2bf(float f) {
    unsigned u = __float_as_uint(f);
    return (unsigned short)((u + 0x7FFFu + ((u >> 16) & 1u)) >> 16);
}
__device__ __forceinline__ float bf2f(unsigned short h) {
    return __uint_as_float(((unsigned)h) << 16);
}

// async global->LDS, 16B per lane; dst_base must be wave-uniform
__device__ __forceinline__ void gload_lds16(const float4* src, float* dst_base) {
#if defined(__has_builtin) && __has_builtin(__builtin_amdgcn_global_load_lds)
    __builtin_amdgcn_global_load_lds((const __attribute__((address_space(1))) void*)src,
                                     (__attribute__((address_space(3))) void*)dst_base,
                                     16, 0, 0);
#else
    ((float4*)dst_base)[threadIdx.x & 63] = *src;
#endif
}

#define P1_SS 1352   // P1 record per sample: [6*14 rows][16] + 8 tail pad

// conv1 + relu + pool2 via bf16 MFMA. 2 samples/block, fp32 DMA staging.
// A rows: (sample<<3)|quad; K = (ci,kp) blocks; 2 weight x-parities, A-shift
// covers the other two conv-x offsets. fp32 128B rows => bank-conflict-free.
__global__ __launch_bounds__(256, 5) void conv1_mfma(
    const float* __restrict__ x, const unsigned short* __restrict__ c1wf,
    const float* __restrict__ c1b, unsigned short* __restrict__ P1)
{
    __shared__ __align__(16) float img[2 * 3072 + 32];        // 24704 B, linear
    __shared__ __align__(16) unsigned short outs[2 * P1_SS];  //  5408 B
    const int t = threadIdx.x;
    const int lane = t & 63, w = t >> 6;
    const int grp = lane >> 4, c = lane & 15;
    const int smp = c >> 3, q = c & 7;

    // zero output staging + img tail pad (row-95 overread lands here)
    for (int e = t; e < 338; e += 256)
        ((uint4*)outs)[e] = make_uint4(0u, 0u, 0u, 0u);
    if (t < 8)
        ((uint4*)img)[1536 + t] = make_uint4(0u, 0u, 0u, 0u);

    // DMA stage: 6144 floats = 24 chunks x 1024B, 6 per wave, fully linear
    const float4* xs4 = (const float4*)(x + (size_t)blockIdx.x * 6144);
#pragma unroll
    for (int k = 0; k < 6; k++) {
        int chunk = w * 6 + k;
        gload_lds16(xs4 + chunk * 64 + lane, &img[chunk * 256]);
    }

    // weight fragments: c1wf[s][off(4)][grp][c][8], use off 0..1 only
    short8 wf[5][2];
#pragma unroll
    for (int s = 0; s < 5; s++)
#pragma unroll
        for (int off = 0; off < 2; off++)
            wf[s][off] = *(const short8*)&c1wf[(((s * 4 + off) * 4 + grp) * 16 + c) * 8];
    int ciA[5], kpA[5];
#pragma unroll
    for (int s = 0; s < 5; s++) {
        int b = s * 4 + grp; if (b > 17) b = 17;   // clamped dup has zero weights
        ciA[s] = b / 6; kpA[s] = b % 6;
    }
    const float bias = (c < 6) ? c1b[c] : 0.f;
    __syncthreads();

    // items = 14 py values over 4 waves
    for (int py = w; py < 14; py += 4) {
        f32x4 a00 = {0.f,0.f,0.f,0.f}, a01 = a00, a10 = a00, a11 = a00;
#pragma unroll
        for (int s = 0; s < 5; s++) {
            int r = smp * 96 + ciA[s] * 32 + py * 2 + kpA[s];
            const float* rp = &img[r * 32 + q * 4];
            float4 fa = *(const float4*)rp;        // cols q*4 .. +3
            float4 fb = *(const float4*)(rp + 4);  // cols q*4+4 .. +7
            float2 fc = *(const float2*)(rp + 8);  // cols q*4+8, +9
            unsigned short h0 = f2bf(fa.x), h1 = f2bf(fa.y), h2 = f2bf(fa.z), h3 = f2bf(fa.w);
            unsigned short h4 = f2bf(fb.x), h5 = f2bf(fb.y), h6 = f2bf(fb.z), h7 = f2bf(fb.w);
            unsigned short h8 = f2bf(fc.x), h9 = f2bf(fc.y);
            short8 A0 = { (short)h0,(short)h1,(short)h2,(short)h3,
                          (short)h4,(short)h5,(short)h6,(short)h7 };
            short8 A2 = { (short)h2,(short)h3,(short)h4,(short)h5,
                          (short)h6,(short)h7,(short)h8,(short)h9 };
            a00 = __builtin_amdgcn_mfma_f32_16x16x32_bf16(A0, wf[s][0], a00, 0, 0, 0);
            a01 = __builtin_amdgcn_mfma_f32_16x16x32_bf16(A0, wf[s][1], a01, 0, 0, 0);
            a10 = __builtin_amdgcn_mfma_f32_16x16x32_bf16(A2, wf[s][0], a10, 0, 0, 0);
            a11 = __builtin_amdgcn_mfma_f32_16x16x32_bf16(A2, wf[s][1], a11, 0, 0, 0);
        }
        // pool x-pairs in-lane (pe: px=q*2, po: px=q*2+1), y-pair via c <-> c+8
        f32x4 pe, po, pe2, po2;
#pragma unroll
        for (int i = 0; i < 4; i++) {
            pe[i] = fmaxf(a00[i], a01[i]);
            po[i] = fmaxf(a10[i], a11[i]);
        }
#pragma unroll
        for (int i = 0; i < 4; i++) {
            pe2[i] = fmaxf(pe[i], __shfl_xor(pe[i], 8));
            po2[i] = fmaxf(po[i], __shfl_xor(po[i], 8));
        }
        if (c < 6) {
#pragma unroll
            for (int i = 0; i < 4; i++) {
                int m = grp * 4 + i;               // D row: sample = m>>3, quad = m&7
                int qo = m & 7;
                if (qo < 7) {
                    int sm = m >> 3;
                    float v0 = fmaxf(pe2[i] + bias, 0.f);
                    float v1 = fmaxf(po2[i] + bias, 0.f);
                    unsigned pk = (unsigned)f2bf(v0) | ((unsigned)f2bf(v1) << 16);
                    *(unsigned*)&outs[sm * P1_SS + (c * 14 + py) * 16 + qo * 2] = pk;
                }
            }
        }
    }
    __syncthreads();

    // coalesced dump: P1 record layout == conv2 LDS layout
    uint4* dst = (uint4*)(P1 + (size_t)blockIdx.x * 2 * P1_SS);
    for (int e = t; e < 338; e += 256)
        dst[e] = ((const uint4*)outs)[e];
}

// conv2 + relu + pool2 via bf16 MFMA. 16 samples/block; staging = pure copy.
__global__ __launch_bounds__(256, 3) void conv2_mfma(
    const unsigned short* __restrict__ P1, const unsigned short* __restrict__ c2wf,
    const float* __restrict__ c2b, unsigned short* __restrict__ P2)
{
    __shared__ __align__(16) unsigned short p1s[16 * P1_SS];  // 43264 B
    const int t = threadIdx.x;
    const int lane = t & 63;
    const int wave = t >> 6;
    const int grp = lane >> 4, c = lane & 15;

    {
        const uint4* src = (const uint4*)(P1 + (size_t)blockIdx.x * 16 * P1_SS);
        uint4* dst = (uint4*)p1s;
        for (int e = t; e < 2704; e += 256) dst[e] = src[e];
    }

    short8 wf[8][2];
#pragma unroll
    for (int s = 0; s < 8; s++)
#pragma unroll
        for (int off = 0; off < 2; off++)
            wf[s][off] = *(const short8*)&c2wf[(((s * 2 + off) * 4 + grp) * 16 + c) * 8];
    int ciA[8], kyA[8];
#pragma unroll
    for (int s = 0; s < 8; s++) {
        int b = s * 4 + grp; if (b > 29) b = 29;
        ciA[s] = b / 5; kyA[s] = b % 5;
    }
    const float bias = c2b[c];
    __syncthreads();

    for (int item = wave; item < 25; item += 4) {
        int py = item / 5, px = item % 5;
        f32x4 a00 = {0.f,0.f,0.f,0.f}, a01 = a00, a10 = a00, a11 = a00;
#pragma unroll
        for (int s = 0; s < 8; s++) {
            int rbase = ciA[s] * 14 + kyA[s] + py * 2;
#pragma unroll
            for (int yo = 0; yo < 2; yo++) {
                int e = c * P1_SS + (rbase + yo) * 16 + px * 2;
                union { unsigned u[4]; short8 v; } af;
                af.u[0] = *(const unsigned*)&p1s[e];
                af.u[1] = *(const unsigned*)&p1s[e + 2];
                af.u[2] = *(const unsigned*)&p1s[e + 4];
                af.u[3] = *(const unsigned*)&p1s[e + 6];
                if (yo == 0) {
                    a00 = __builtin_amdgcn_mfma_f32_16x16x32_bf16(af.v, wf[s][0], a00, 0, 0, 0);
                    a01 = __builtin_amdgcn_mfma_f32_16x16x32_bf16(af.v, wf[s][1], a01, 0, 0, 0);
                } else {
                    a10 = __builtin_amdgcn_mfma_f32_16x16x32_bf16(af.v, wf[s][0], a10, 0, 0, 0);
                    a11 = __builtin_amdgcn_mfma_f32_16x16x32_bf16(af.v, wf[s][1], a11, 0, 0, 0);
                }
            }
        }
#pragma unroll
        for (int i = 0; i < 4; i++) {
            float mx = fmaxf(fmaxf(a00[i], a01[i]), fmaxf(a10[i], a11[i]));
            float v = fmaxf(mx + bias, 0.f);
            int n = blockIdx.x * 16 + grp * 4 + i;
            P2[(size_t)n * 400 + c * 25 + py * 5 + px] = f2bf(v);
        }
    }
}

// one-shot conversion: FC weights to padded bf16 tiles + conv weight fragments
__global__ __launch_bounds__(256) void prep_weights(
    const float* __restrict__ c1w, const float* __restrict__ c2w,
    const float* __restrict__ f1w, const float* __restrict__ f2w,
    const float* __restrict__ f3w,
    unsigned short* __restrict__ wb1, unsigned short* __restrict__ wb2,
    unsigned short* __restrict__ wb3,
    unsigned short* __restrict__ c1wf, unsigned short* __restrict__ c2wf)
{
    const int t0 = blockIdx.x * 256 + threadIdx.x;
    const int stride = gridDim.x * 256;
    for (int i = t0; i < 128 * 416; i += stride) {
        int o = i / 416, k = i % 416;
        wb1[i] = f2bf((o < 120 && k < 400) ? f1w[o * 400 + k] : 0.f);
    }
    for (int i = t0; i < 96 * 128; i += stride) {
        int o = i / 128, k = i % 128;
        wb2[i] = f2bf((o < 84 && k < 120) ? f2w[o * 120 + k] : 0.f);
    }
    for (int i = t0; i < 64 * 96; i += stride) {
        int o = i / 96, k = i % 96;
        wb3[i] = f2bf((k < 84) ? f3w[o * 84 + k] : 0.f);
    }
    // c1wf[s(5)][off(4)][grp(4)][c(16)][j(8)]
    for (int i = t0; i < 10240; i += stride) {
        int j = i & 7, c = (i >> 3) & 15, grp = (i >> 7) & 3;
        int off = (i >> 9) & 3, s = i >> 11;
        int b = s * 4 + grp;
        int ci = b / 6, kp = b % 6;
        int kx = j - off;
        float v = 0.f;
        if (b < 18 && kx >= 0 && kx <= 4) {
            if (c < 6 && kp <= 4)
                v = c1w[c * 75 + ci * 25 + kp * 5 + kx];
            else if (c >= 8 && c < 14 && kp >= 1)
                v = c1w[(c - 8) * 75 + ci * 25 + (kp - 1) * 5 + kx];
        }
        c1wf[i] = f2bf(v);
    }
    // c2wf[s(8)][off(2)][grp(4)][c(16)][j(8)]
    for (int i = t0; i < 8192; i += stride) {
        int j = i & 7, c = (i >> 3) & 15, grp = (i >> 7) & 3;
        int off = (i >> 9) & 1, s = i >> 10;
        int b = s * 4 + grp;
        int kx = j - off;
        float v = 0.f;
        if (b < 30 && kx >= 0 && kx <= 4) {
            int ci = b / 5, ky = b % 5;
            v = c2w[c * 150 + ci * 25 + ky * 5 + kx];
        }
        c2wf[i] = f2bf(v);
    }
}

#define FCS 32
#define P2S 424
#define A1S 136
#define A2S 104

// FC1->FC2->FC3 via bf16 MFMA
__global__ __launch_bounds__(256, 3) void fc_mfma(
    const unsigned short* __restrict__ P2,
    const unsigned short* __restrict__ wb1, const float* __restrict__ f1b,
    const unsigned short* __restrict__ wb2, const float* __restrict__ f2b,
    const unsigned short* __restrict__ wb3, const float* __restrict__ f3b,
    float* __restrict__ emb)
{
    __shared__ __align__(16) unsigned short p2s[FCS * P2S];
    __shared__ __align__(16) unsigned short a1s[FCS * A1S];
    __shared__ __align__(16) unsigned short a2s[FCS * A2S];
    const int t = threadIdx.x, lane = t & 63, w = t >> 6;
    const int grp = lane >> 4, c = lane & 15;

    if (t < 64) {
        int s = t >> 1, h = t & 1;
        *(uint4*)&p2s[s * P2S + 400 + h * 8] = make_uint4(0u, 0u, 0u, 0u);
    }
    const uint4* src = (const uint4*)(P2 + (size_t)blockIdx.x * FCS * 400);
    for (int i = t; i < FCS * 50; i += 256) {
        int s = i / 50, k8 = i % 50;
        *(uint4*)&p2s[s * P2S + k8 * 8] = src[i];
    }
    __syncthreads();

    const int m = w & 1;
    const int arow = m * 16 + c;

    {
        const int n0 = (w >> 1) * 4;
        f32x4 acc[4] = {{0.f,0.f,0.f,0.f},{0.f,0.f,0.f,0.f},{0.f,0.f,0.f,0.f},{0.f,0.f,0.f,0.f}};
        const int sb = arow * P2S;
#pragma unroll
        for (int ks = 0; ks < 13; ks++) {
            short8 a = *(const short8*)&p2s[sb + ks * 32 + grp * 8];
#pragma unroll
            for (int j = 0; j < 4; j++) {
                int o = (n0 + j) * 16 + c;
                short8 b = *(const short8*)&wb1[o * 416 + ks * 32 + grp * 8];
                acc[j] = __builtin_amdgcn_mfma_f32_16x16x32_bf16(a, b, acc[j], 0, 0, 0);
            }
        }
#pragma unroll
        for (int j = 0; j < 4; j++) {
            int o = (n0 + j) * 16 + c;
            float bias = (o < 120) ? f1b[o] : 0.f;
#pragma unroll
            for (int i = 0; i < 4; i++) {
                int s = m * 16 + grp * 4 + i;
                a1s[s * A1S + o] = f2bf(fmaxf(acc[j][i] + bias, 0.f));
            }
        }
    }
    __syncthreads();

    {
        const int n0 = (w >> 1) * 3;
        f32x4 acc[3] = {{0.f,0.f,0.f,0.f},{0.f,0.f,0.f,0.f},{0.f,0.f,0.f,0.f}};
        const int sb = arow * A1S;
#pragma unroll
        for (int ks = 0; ks < 4; ks++) {
            short8 a = *(const short8*)&a1s[sb + ks * 32 + grp * 8];
#pragma unroll
            for (int j = 0; j < 3; j++) {
                int o = (n0 + j) * 16 + c;
                short8 b = *(const short8*)&wb2[o * 128 + ks * 32 + grp * 8];
                acc[j] = __builtin_amdgcn_mfma_f32_16x16x32_bf16(a, b, acc[j], 0, 0, 0);
            }
        }
#pragma unroll
        for (int j = 0; j < 3; j++) {
            int o = (n0 + j) * 16 + c;
            float bias = (o < 84) ? f2b[o] : 0.f;
#pragma unroll
            for (int i = 0; i < 4; i++) {
                int s = m * 16 + grp * 4 + i;
                a2s[s * A2S + o] = f2bf(fmaxf(acc[j][i] + bias, 0.f));
            }
        }
    }
    __syncthreads();

    {
        const int n0 = (w >> 1) * 2;
        f32x4 acc[2] = {{0.f,0.f,0.f,0.f},{0.f,0.f,0.f,0.f}};
        const int sb = arow * A2S;
#pragma unroll
        for (int ks = 0; ks < 3; ks++) {
            short8 a = *(const short8*)&a2s[sb + ks * 32 + grp * 8];
#pragma unroll
            for (int j = 0; j < 2; j++) {
                int o = (n0 + j) * 16 + c;
                short8 b = *(const short8*)&wb3[o * 96 + ks * 32 + grp * 8];
                acc[j] = __builtin_amdgcn_mfma_f32_16x16x32_bf16(a, b, acc[j], 0, 0, 0);
            }
        }
#pragma unroll
        for (int j = 0; j < 2; j++) {
            int o = (n0 + j) * 16 + c;
            float bias = f3b[o];
#pragma unroll
            for (int i = 0; i < 4; i++) {
                int s = m * 16 + grp * 4 + i;
                emb[((size_t)blockIdx.x * FCS + s) * 64 + o] = acc[j][i] + bias;
            }
        }
    }
}

__global__ __launch_bounds__(256) void reduce_emb(const float* __restrict__ emb,
                                                  float* __restrict__ part, int total) {
    __shared__ float s_[256];
    const int t = threadIdx.x;
    const int chunk = total / 256;
    const float* base = emb + (size_t)blockIdx.x * chunk;
    float s = 0.f;
    for (int j = t; j < chunk; j += 256) s += base[j];
    s_[t] = s; __syncthreads();
    for (int off = 128; off > 0; off >>= 1) {
        if (t < off) s_[t] += s_[t + off];
        __syncthreads();
    }
    if (t == 0) part[blockIdx.x] = s_[0];
}

__global__ __launch_bounds__(256) void reduce_part(const float* __restrict__ part,
                                                   float* __restrict__ proto) {
    __shared__ float s_[256];
    const int t = threadIdx.x;
    s_[t] = part[t]; __syncthreads();
    for (int off = 128; off > 0; off >>= 1) {
        if (t < off) s_[t] += s_[t + off];
        __syncthreads();
    }
    if (t == 0) proto[0] = s_[0] / 5.0f;
}

__global__ __launch_bounds__(256) void softmax_abs(float* __restrict__ io,
                                                   const float* __restrict__ proto_p) {
    const int lane = threadIdx.x & 63;
    const int row = (blockIdx.x << 2) + (threadIdx.x >> 6);
    const float proto = proto_p[0];
    float e = io[(size_t)row * 64 + lane];
    float m = e;
#pragma unroll
    for (int off = 32; off; off >>= 1) m = fmaxf(m, __shfl_xor(m, off));
    float p = expf(e - m);
    float s = p;
#pragma unroll
    for (int off = 32; off; off >>= 1) s += __shfl_xor(s, off);
    io[(size_t)row * 64 + lane] = fabsf(p / s - proto);
}

extern "C" void kernel_launch(void* const* d_in, const int* in_sizes, int n_in,
                              void* d_out, int out_size, void* d_ws, size_t ws_size,
                              hipStream_t stream) {
    const float* x   = (const float*)d_in[0];
    const float* c1w = (const float*)d_in[1];
    const float* c1b = (const float*)d_in[2];
    const float* c2w = (const float*)d_in[3];
    const float* c2b = (const float*)d_in[4];
    const float* f1w = (const float*)d_in[5];
    const float* f1b = (const float*)d_in[6];
    const float* f2w = (const float*)d_in[7];
    const float* f2b = (const float*)d_in[8];
    const float* f3w = (const float*)d_in[9];
    const float* f3b = (const float*)d_in[10];
    float* out = (float*)d_out;

    const int N = in_sizes[0] / 3072;                 // 20480
    const size_t p1_bytes = (size_t)N * P1_SS * 2;    // 55.4 MB
    const size_t p2_bytes = (size_t)N * 400 * 2;      // 16.4 MB
    unsigned short* P1 = (unsigned short*)d_ws;
    unsigned short* P2 = (unsigned short*)((char*)d_ws + p1_bytes);
    char* tail = (char*)d_ws + p1_bytes + p2_bytes;
    float* part  = (float*)tail;                      // 256 floats
    float* proto = part + 256;                        // 1 float
    unsigned short* wb1  = (unsigned short*)(tail + 2048);  // 128x416
    unsigned short* wb2  = wb1 + 128 * 416;                 // 96x128
    unsigned short* wb3  = wb2 + 96 * 128;                  // 64x96
    unsigned short* c1wf = wb3 + 64 * 96;                   // 10240
    unsigned short* c2wf = c1wf + 10240;                    // 8192

    prep_weights<<<64, 256, 0, stream>>>(c1w, c2w, f1w, f2w, f3w,
                                         wb1, wb2, wb3, c1wf, c2wf);
    conv1_mfma<<<N / 2, 256, 0, stream>>>(x, c1wf, c1b, P1);
    conv2_mfma<<<N / 16, 256, 0, stream>>>(P1, c2wf, c2b, P2);
    fc_mfma<<<N / 32, 256, 0, stream>>>(P2, wb1, f1b, wb2, f2b, wb3, f3b, out);
    reduce_emb<<<256, 256, 0, stream>>>(out, part, N * 64);
    reduce_part<<<1, 256, 0, stream>>>(part, proto);
    softmax_abs<<<N / 4, 256, 0, stream>>>(out, proto);
}

// Round 9
// 156.475 us; speedup vs baseline: 1.1255x; 1.1255x over previous
//
#include <hip/hip_runtime.h>
#include <math.h>

typedef __attribute__((ext_vector_type(8))) short short8;
typedef __attribute__((ext_vector_type(4))) float f32x4;
typedef __attribute__((ext_vector_type(4))) unsigned short us4v;

__device__ __forceinline__ unsigned short f2bf(float f) {
    unsigned u = __float_as_uint(f);
    return (unsigned short)((u + 0x7FFFu + ((u >> 16) & 1u)) >> 16);
}
__device__ __forceinline__ float bf2f(unsigned short h) {
    return __uint_as_float(((unsigned)h) << 16);
}

#define P1_SS 1352   // P1 record per sample: [6*14 rows][16] + 8 tail pad
#define C1T_SS 3464  // conv1 LDS elems per sample (96 rows x 36 + 8 tail)
#define C1_RS 36     // conv1 LDS row stride (32 data + 4 pad)

// conv1 + relu + pool2 via bf16 MFMA. 4 samples/block as TWO pipelined
// 2-sample tiles: tile1's global loads issue before tile0's compute, so
// HBM latency hides under MFMA. Conversion happens ONCE per element at
// staging. (R8 bug: outs zero/dump loops used 169 uint4 = ONE sample;
// a tile is TWO samples = 338 uint4 - odd samples never reached P1.)
__global__ __launch_bounds__(256, 4) void conv1_mfma(
    const float* __restrict__ x, const unsigned short* __restrict__ c1wf,
    const float* __restrict__ c1b, unsigned short* __restrict__ P1)
{
    __shared__ __align__(16) unsigned short img[2 * C1T_SS];   // 13856 B (one tile)
    __shared__ __align__(16) unsigned short outs[2 * P1_SS];   //  5408 B (one tile)
    const int t = threadIdx.x;
    const int lane = t & 63, w = t >> 6;
    const int grp = lane >> 4, c = lane & 15;
    const int smp = c >> 3, q = c & 7;

    // zero pads once: outs fully (338 uint4 = 2 samples); img row pads + tails.
    // compute/staging never touch pads, so they stay zero across both tiles.
    for (int e = t; e < 338; e += 256)
        ((uint4*)outs)[e] = make_uint4(0u, 0u, 0u, 0u);
    if (t < 192) {
        int s = t / 96, rr = t - s * 96;
        *(uint2*)&img[s * C1T_SS + rr * C1_RS + 32] = make_uint2(0u, 0u);
    }
    if (t < 2)
        *(uint4*)&img[t * C1T_SS + 3456] = make_uint4(0u, 0u, 0u, 0u);

    // weight fragments: c1wf[s][off(4)][grp][c][8], use off 0..1 only
    short8 wf[5][2];
#pragma unroll
    for (int s = 0; s < 5; s++)
#pragma unroll
        for (int off = 0; off < 2; off++)
            wf[s][off] = *(const short8*)&c1wf[(((s * 4 + off) * 4 + grp) * 16 + c) * 8];
    int ciA[5], kpA[5];
#pragma unroll
    for (int s = 0; s < 5; s++) {
        int b = s * 4 + grp; if (b > 17) b = 17;   // clamped dup has zero weights
        ciA[s] = b / 6; kpA[s] = b % 6;
    }
    const float bias = (c < 6) ? c1b[c] : 0.f;

    const float4* xs4 = (const float4*)(x + (size_t)blockIdx.x * 12288);
    float4 r[6];

    // ---- load tile0 ----
#pragma unroll
    for (int k = 0; k < 6; k++) r[k] = xs4[k * 256 + t];

#pragma unroll
    for (int tile = 0; tile < 2; tile++) {
        // convert + write current tile (1x per element)
#pragma unroll
        for (int k = 0; k < 6; k++) {
            int f = k * 256 + t;                  // 0..1535
            int s = (f >= 768) ? 1 : 0;
            int w4 = f - s * 768;
            int ci = w4 >> 8, rem = w4 & 255, y = rem >> 3, xq = rem & 7;
            us4v pk = { f2bf(r[k].x), f2bf(r[k].y), f2bf(r[k].z), f2bf(r[k].w) };
            *(us4v*)&img[s * C1T_SS + (ci * 32 + y) * C1_RS + xq * 4] = pk;
        }
        __syncthreads();

        // issue next tile's loads (in flight during this tile's compute)
        if (tile == 0) {
#pragma unroll
            for (int k = 0; k < 6; k++) r[k] = xs4[1536 + k * 256 + t];
        }

        // ---- compute: 14 py items over 4 waves ----
        for (int py = w; py < 14; py += 4) {
            f32x4 a00 = {0.f,0.f,0.f,0.f}, a01 = a00, a10 = a00, a11 = a00;
#pragma unroll
            for (int s = 0; s < 5; s++) {
                int e = smp * C1T_SS + (ciA[s] * 32 + py * 2 + kpA[s]) * C1_RS + q * 4;
                us4v h0 = *(const us4v*)&img[e];
                us4v h1 = *(const us4v*)&img[e + 4];
                ushort2 h2 = *(const ushort2*)&img[e + 8];
                short8 A0 = { (short)h0[0],(short)h0[1],(short)h0[2],(short)h0[3],
                              (short)h1[0],(short)h1[1],(short)h1[2],(short)h1[3] };
                short8 A2 = { (short)h0[2],(short)h0[3],(short)h1[0],(short)h1[1],
                              (short)h1[2],(short)h1[3],(short)h2.x,(short)h2.y };
                a00 = __builtin_amdgcn_mfma_f32_16x16x32_bf16(A0, wf[s][0], a00, 0, 0, 0);
                a01 = __builtin_amdgcn_mfma_f32_16x16x32_bf16(A0, wf[s][1], a01, 0, 0, 0);
                a10 = __builtin_amdgcn_mfma_f32_16x16x32_bf16(A2, wf[s][0], a10, 0, 0, 0);
                a11 = __builtin_amdgcn_mfma_f32_16x16x32_bf16(A2, wf[s][1], a11, 0, 0, 0);
            }
            // pool x-pairs in-lane (pe: px=q*2, po: px=q*2+1), y-pair via c <-> c+8
            f32x4 pe, po, pe2, po2;
#pragma unroll
            for (int i = 0; i < 4; i++) {
                pe[i] = fmaxf(a00[i], a01[i]);
                po[i] = fmaxf(a10[i], a11[i]);
            }
#pragma unroll
            for (int i = 0; i < 4; i++) {
                pe2[i] = fmaxf(pe[i], __shfl_xor(pe[i], 8));
                po2[i] = fmaxf(po[i], __shfl_xor(po[i], 8));
            }
            if (c < 6) {
#pragma unroll
                for (int i = 0; i < 4; i++) {
                    int m = grp * 4 + i;           // D row: sample = m>>3, quad = m&7
                    int qo = m & 7;
                    if (qo < 7) {
                        int sm = m >> 3;
                        float v0 = fmaxf(pe2[i] + bias, 0.f);
                        float v1 = fmaxf(po2[i] + bias, 0.f);
                        unsigned pk = (unsigned)f2bf(v0) | ((unsigned)f2bf(v1) << 16);
                        *(unsigned*)&outs[sm * P1_SS + (c * 14 + py) * 16 + qo * 2] = pk;
                    }
                }
            }
        }
        __syncthreads();   // img reads + outs writes complete

        // coalesced dump of this tile's 2 samples (layout == conv2 LDS layout)
        uint4* dst = (uint4*)(P1 + ((size_t)blockIdx.x * 4 + tile * 2) * P1_SS);
        for (int e = t; e < 338; e += 256)
            dst[e] = ((const uint4*)outs)[e];
        if (tile == 0) __syncthreads();  // dump done before tile1 overwrites outs/img
    }
}

// conv2 + relu + pool2 via bf16 MFMA. 16 samples/block; staging = pure copy.
__global__ __launch_bounds__(256, 3) void conv2_mfma(
    const unsigned short* __restrict__ P1, const unsigned short* __restrict__ c2wf,
    const float* __restrict__ c2b, unsigned short* __restrict__ P2)
{
    __shared__ __align__(16) unsigned short p1s[16 * P1_SS];  // 43264 B
    const int t = threadIdx.x;
    const int lane = t & 63;
    const int wave = t >> 6;
    const int grp = lane >> 4, c = lane & 15;

    {
        const uint4* src = (const uint4*)(P1 + (size_t)blockIdx.x * 16 * P1_SS);
        uint4* dst = (uint4*)p1s;
        for (int e = t; e < 2704; e += 256) dst[e] = src[e];
    }

    short8 wf[8][2];
#pragma unroll
    for (int s = 0; s < 8; s++)
#pragma unroll
        for (int off = 0; off < 2; off++)
            wf[s][off] = *(const short8*)&c2wf[(((s * 2 + off) * 4 + grp) * 16 + c) * 8];
    int ciA[8], kyA[8];
#pragma unroll
    for (int s = 0; s < 8; s++) {
        int b = s * 4 + grp; if (b > 29) b = 29;
        ciA[s] = b / 5; kyA[s] = b % 5;
    }
    const float bias = c2b[c];
    __syncthreads();

    for (int item = wave; item < 25; item += 4) {
        int py = item / 5, px = item % 5;
        f32x4 a00 = {0.f,0.f,0.f,0.f}, a01 = a00, a10 = a00, a11 = a00;
#pragma unroll
        for (int s = 0; s < 8; s++) {
            int rbase = ciA[s] * 14 + kyA[s] + py * 2;
#pragma unroll
            for (int yo = 0; yo < 2; yo++) {
                int e = c * P1_SS + (rbase + yo) * 16 + px * 2;
                union { unsigned u[4]; short8 v; } af;
                af.u[0] = *(const unsigned*)&p1s[e];
                af.u[1] = *(const unsigned*)&p1s[e + 2];
                af.u[2] = *(const unsigned*)&p1s[e + 4];
                af.u[3] = *(const unsigned*)&p1s[e + 6];
                if (yo == 0) {
                    a00 = __builtin_amdgcn_mfma_f32_16x16x32_bf16(af.v, wf[s][0], a00, 0, 0, 0);
                    a01 = __builtin_amdgcn_mfma_f32_16x16x32_bf16(af.v, wf[s][1], a01, 0, 0, 0);
                } else {
                    a10 = __builtin_amdgcn_mfma_f32_16x16x32_bf16(af.v, wf[s][0], a10, 0, 0, 0);
                    a11 = __builtin_amdgcn_mfma_f32_16x16x32_bf16(af.v, wf[s][1], a11, 0, 0, 0);
                }
            }
        }
#pragma unroll
        for (int i = 0; i < 4; i++) {
            float mx = fmaxf(fmaxf(a00[i], a01[i]), fmaxf(a10[i], a11[i]));
            float v = fmaxf(mx + bias, 0.f);
            int n = blockIdx.x * 16 + grp * 4 + i;
            P2[(size_t)n * 400 + c * 25 + py * 5 + px] = f2bf(v);
        }
    }
}

// one-shot conversion: FC weights to padded bf16 tiles + conv weight fragments
__global__ __launch_bounds__(256) void prep_weights(
    const float* __restrict__ c1w, const float* __restrict__ c2w,
    const float* __restrict__ f1w, const float* __restrict__ f2w,
    const float* __restrict__ f3w,
    unsigned short* __restrict__ wb1, unsigned short* __restrict__ wb2,
    unsigned short* __restrict__ wb3,
    unsigned short* __restrict__ c1wf, unsigned short* __restrict__ c2wf)
{
    const int t0 = blockIdx.x * 256 + threadIdx.x;
    const int stride = gridDim.x * 256;
    for (int i = t0; i < 128 * 416; i += stride) {
        int o = i / 416, k = i % 416;
        wb1[i] = f2bf((o < 120 && k < 400) ? f1w[o * 400 + k] : 0.f);
    }
    for (int i = t0; i < 96 * 128; i += stride) {
        int o = i / 128, k = i % 128;
        wb2[i] = f2bf((o < 84 && k < 120) ? f2w[o * 120 + k] : 0.f);
    }
    for (int i = t0; i < 64 * 96; i += stride) {
        int o = i / 96, k = i % 96;
        wb3[i] = f2bf((k < 84) ? f3w[o * 84 + k] : 0.f);
    }
    // c1wf[s(5)][off(4)][grp(4)][c(16)][j(8)]
    for (int i = t0; i < 10240; i += stride) {
        int j = i & 7, c = (i >> 3) & 15, grp = (i >> 7) & 3;
        int off = (i >> 9) & 3, s = i >> 11;
        int b = s * 4 + grp;
        int ci = b / 6, kp = b % 6;
        int kx = j - off;
        float v = 0.f;
        if (b < 18 && kx >= 0 && kx <= 4) {
            if (c < 6 && kp <= 4)
                v = c1w[c * 75 + ci * 25 + kp * 5 + kx];
            else if (c >= 8 && c < 14 && kp >= 1)
                v = c1w[(c - 8) * 75 + ci * 25 + (kp - 1) * 5 + kx];
        }
        c1wf[i] = f2bf(v);
    }
    // c2wf[s(8)][off(2)][grp(4)][c(16)][j(8)]
    for (int i = t0; i < 8192; i += stride) {
        int j = i & 7, c = (i >> 3) & 15, grp = (i >> 7) & 3;
        int off = (i >> 9) & 1, s = i >> 10;
        int b = s * 4 + grp;
        int kx = j - off;
        float v = 0.f;
        if (b < 30 && kx >= 0 && kx <= 4) {
            int ci = b / 5, ky = b % 5;
            v = c2w[c * 150 + ci * 25 + ky * 5 + kx];
        }
        c2wf[i] = f2bf(v);
    }
}

#define FCS 32
#define P2S 424
#define A1S 136
#define A2S 104

// FC1->FC2->FC3 via bf16 MFMA
__global__ __launch_bounds__(256, 3) void fc_mfma(
    const unsigned short* __restrict__ P2,
    const unsigned short* __restrict__ wb1, const float* __restrict__ f1b,
    const unsigned short* __restrict__ wb2, const float* __restrict__ f2b,
    const unsigned short* __restrict__ wb3, const float* __restrict__ f3b,
    float* __restrict__ emb)
{
    __shared__ __align__(16) unsigned short p2s[FCS * P2S];
    __shared__ __align__(16) unsigned short a1s[FCS * A1S];
    __shared__ __align__(16) unsigned short a2s[FCS * A2S];
    const int t = threadIdx.x, lane = t & 63, w = t >> 6;
    const int grp = lane >> 4, c = lane & 15;

    if (t < 64) {
        int s = t >> 1, h = t & 1;
        *(uint4*)&p2s[s * P2S + 400 + h * 8] = make_uint4(0u, 0u, 0u, 0u);
    }
    const uint4* src = (const uint4*)(P2 + (size_t)blockIdx.x * FCS * 400);
    for (int i = t; i < FCS * 50; i += 256) {
        int s = i / 50, k8 = i % 50;
        *(uint4*)&p2s[s * P2S + k8 * 8] = src[i];
    }
    __syncthreads();

    const int m = w & 1;
    const int arow = m * 16 + c;

    {
        const int n0 = (w >> 1) * 4;
        f32x4 acc[4] = {{0.f,0.f,0.f,0.f},{0.f,0.f,0.f,0.f},{0.f,0.f,0.f,0.f},{0.f,0.f,0.f,0.f}};
        const int sb = arow * P2S;
#pragma unroll
        for (int ks = 0; ks < 13; ks++) {
            short8 a = *(const short8*)&p2s[sb + ks * 32 + grp * 8];
#pragma unroll
            for (int j = 0; j < 4; j++) {
                int o = (n0 + j) * 16 + c;
                short8 b = *(const short8*)&wb1[o * 416 + ks * 32 + grp * 8];
                acc[j] = __builtin_amdgcn_mfma_f32_16x16x32_bf16(a, b, acc[j], 0, 0, 0);
            }
        }
#pragma unroll
        for (int j = 0; j < 4; j++) {
            int o = (n0 + j) * 16 + c;
            float bias = (o < 120) ? f1b[o] : 0.f;
#pragma unroll
            for (int i = 0; i < 4; i++) {
                int s = m * 16 + grp * 4 + i;
                a1s[s * A1S + o] = f2bf(fmaxf(acc[j][i] + bias, 0.f));
            }
        }
    }
    __syncthreads();

    {
        const int n0 = (w >> 1) * 3;
        f32x4 acc[3] = {{0.f,0.f,0.f,0.f},{0.f,0.f,0.f,0.f},{0.f,0.f,0.f,0.f}};
        const int sb = arow * A1S;
#pragma unroll
        for (int ks = 0; ks < 4; ks++) {
            short8 a = *(const short8*)&a1s[sb + ks * 32 + grp * 8];
#pragma unroll
            for (int j = 0; j < 3; j++) {
                int o = (n0 + j) * 16 + c;
                short8 b = *(const short8*)&wb2[o * 128 + ks * 32 + grp * 8];
                acc[j] = __builtin_amdgcn_mfma_f32_16x16x32_bf16(a, b, acc[j], 0, 0, 0);
            }
        }
#pragma unroll
        for (int j = 0; j < 3; j++) {
            int o = (n0 + j) * 16 + c;
            float bias = (o < 84) ? f2b[o] : 0.f;
#pragma unroll
            for (int i = 0; i < 4; i++) {
                int s = m * 16 + grp * 4 + i;
                a2s[s * A2S + o] = f2bf(fmaxf(acc[j][i] + bias, 0.f));
            }
        }
    }
    __syncthreads();

    {
        const int n0 = (w >> 1) * 2;
        f32x4 acc[2] = {{0.f,0.f,0.f,0.f},{0.f,0.f,0.f,0.f}};
        const int sb = arow * A2S;
#pragma unroll
        for (int ks = 0; ks < 3; ks++) {
            short8 a = *(const short8*)&a2s[sb + ks * 32 + grp * 8];
#pragma unroll
            for (int j = 0; j < 2; j++) {
                int o = (n0 + j) * 16 + c;
                short8 b = *(const short8*)&wb3[o * 96 + ks * 32 + grp * 8];
                acc[j] = __builtin_amdgcn_mfma_f32_16x16x32_bf16(a, b, acc[j], 0, 0, 0);
            }
        }
#pragma unroll
        for (int j = 0; j < 2; j++) {
            int o = (n0 + j) * 16 + c;
            float bias = f3b[o];
#pragma unroll
            for (int i = 0; i < 4; i++) {
                int s = m * 16 + grp * 4 + i;
                emb[((size_t)blockIdx.x * FCS + s) * 64 + o] = acc[j][i] + bias;
            }
        }
    }
}

__global__ __launch_bounds__(256) void reduce_emb(const float* __restrict__ emb,
                                                  float* __restrict__ part, int total) {
    __shared__ float s_[256];
    const int t = threadIdx.x;
    const int chunk = total / 256;
    const float* base = emb + (size_t)blockIdx.x * chunk;
    float s = 0.f;
    for (int j = t; j < chunk; j += 256) s += base[j];
    s_[t] = s; __syncthreads();
    for (int off = 128; off > 0; off >>= 1) {
        if (t < off) s_[t] += s_[t + off];
        __syncthreads();
    }
    if (t == 0) part[blockIdx.x] = s_[0];
}

__global__ __launch_bounds__(256) void reduce_part(const float* __restrict__ part,
                                                   float* __restrict__ proto) {
    __shared__ float s_[256];
    const int t = threadIdx.x;
    s_[t] = part[t]; __syncthreads();
    for (int off = 128; off > 0; off >>= 1) {
        if (t < off) s_[t] += s_[t + off];
        __syncthreads();
    }
    if (t == 0) proto[0] = s_[0] / 5.0f;
}

__global__ __launch_bounds__(256) void softmax_abs(float* __restrict__ io,
                                                   const float* __restrict__ proto_p) {
    const int lane = threadIdx.x & 63;
    const int row = (blockIdx.x << 2) + (threadIdx.x >> 6);
    const float proto = proto_p[0];
    float e = io[(size_t)row * 64 + lane];
    float m = e;
#pragma unroll
    for (int off = 32; off; off >>= 1) m = fmaxf(m, __shfl_xor(m, off));
    float p = expf(e - m);
    float s = p;
#pragma unroll
    for (int off = 32; off; off >>= 1) s += __shfl_xor(s, off);
    io[(size_t)row * 64 + lane] = fabsf(p / s - proto);
}

extern "C" void kernel_launch(void* const* d_in, const int* in_sizes, int n_in,
                              void* d_out, int out_size, void* d_ws, size_t ws_size,
                              hipStream_t stream) {
    const float* x   = (const float*)d_in[0];
    const float* c1w = (const float*)d_in[1];
    const float* c1b = (const float*)d_in[2];
    const float* c2w = (const float*)d_in[3];
    const float* c2b = (const float*)d_in[4];
    const float* f1w = (const float*)d_in[5];
    const float* f1b = (const float*)d_in[6];
    const float* f2w = (const float*)d_in[7];
    const float* f2b = (const float*)d_in[8];
    const float* f3w = (const float*)d_in[9];
    const float* f3b = (const float*)d_in[10];
    float* out = (float*)d_out;

    const int N = in_sizes[0] / 3072;                 // 20480
    const size_t p1_bytes = (size_t)N * P1_SS * 2;    // 55.4 MB
    const size_t p2_bytes = (size_t)N * 400 * 2;      // 16.4 MB
    unsigned short* P1 = (unsigned short*)d_ws;
    unsigned short* P2 = (unsigned short*)((char*)d_ws + p1_bytes);
    char* tail = (char*)d_ws + p1_bytes + p2_bytes;
    float* part  = (float*)tail;                      // 256 floats
    float* proto = part + 256;                        // 1 float
    unsigned short* wb1  = (unsigned short*)(tail + 2048);  // 128x416
    unsigned short* wb2  = wb1 + 128 * 416;                 // 96x128
    unsigned short* wb3  = wb2 + 96 * 128;                  // 64x96
    unsigned short* c1wf = wb3 + 64 * 96;                   // 10240
    unsigned short* c2wf = c1wf + 10240;                    // 8192

    prep_weights<<<64, 256, 0, stream>>>(c1w, c2w, f1w, f2w, f3w,
                                         wb1, wb2, wb3, c1wf, c2wf);
    conv1_mfma<<<N / 4, 256, 0, stream>>>(x, c1wf, c1b, P1);
    conv2_mfma<<<N / 16, 256, 0, stream>>>(P1, c2wf, c2b, P2);
    fc_mfma<<<N / 32, 256, 0, stream>>>(P2, wb1, f1b, wb2, f2b, wb3, f3b, out);
    reduce_emb<<<256, 256, 0, stream>>>(out, part, N * 64);
    reduce_part<<<1, 256, 0, stream>>>(part, proto);
    softmax_abs<<<N / 4, 256, 0, stream>>>(out, proto);
}

// Round 10
// 129.594 us; speedup vs baseline: 1.3589x; 1.2074x over previous
//
#include <hip/hip_runtime.h>
#include <math.h>

typedef __attribute__((ext_vector_type(8))) short short8;
typedef __attribute__((ext_vector_type(4))) float f32x4;
typedef __attribute__((ext_vector_type(4))) unsigned short us4v;

__device__ __forceinline__ unsigned short f2bf(float f) {
    unsigned u = __float_as_uint(f);
    return (unsigned short)((u + 0x7FFFu + ((u >> 16) & 1u)) >> 16);
}
__device__ __forceinline__ float bf2f(unsigned short h) {
    return __uint_as_float(((unsigned)h) << 16);
}

#define C1T_SS 3464  // conv1 img LDS elems per sample (96 rows x 36 + 8 tail)
#define C1_RS 36     // conv1 img LDS row stride (32 data + 4 pad)
#define P1R 1176     // p1 record per sample: 84 rows x 14 (stride 14)

// Fused conv1+pool -> conv2+pool via bf16 MFMA. 16 samples/block.
// conv1: 8 register-pipelined 2-sample subtiles, pooled output written
// DIRECTLY to LDS p1s (conv2's consumption layout, stride-14 rows).
// conv2 reads p1s in place. P1 global round-trip (110 MB) eliminated.
// Fragment x-overreads (j>=6) hit zero-weight slots: kx=j-off in [0,4]
// => nonzero j <= off+4 <= 5 => x <= 13, inside the 14-elem row.
__global__ __launch_bounds__(256, 3) void conv12_mfma(
    const float* __restrict__ x,
    const unsigned short* __restrict__ c1wf, const float* __restrict__ c1b,
    const unsigned short* __restrict__ c2wf, const float* __restrict__ c2b,
    unsigned short* __restrict__ P2)
{
    __shared__ __align__(16) unsigned short img[2 * C1T_SS];    // 13856 B
    __shared__ __align__(16) unsigned short p1s[16 * P1R + 16]; // 37664 B
    const int t = threadIdx.x;
    const int lane = t & 63, w = t >> 6;
    const int grp = lane >> 4, c = lane & 15;
    const int smp = c >> 3, q = c & 7;

    // zero img row pads (2x96 rows, elems 32..35) + sample tails + p1s tail pad
    if (t < 192) {
        int s = t / 96, rr = t - s * 96;
        *(uint2*)&img[s * C1T_SS + rr * C1_RS + 32] = make_uint2(0u, 0u);
    }
    if (t < 2) {
        *(uint4*)&img[t * C1T_SS + 3456] = make_uint4(0u, 0u, 0u, 0u);
        *(uint4*)&p1s[16 * P1R + t * 8] = make_uint4(0u, 0u, 0u, 0u);
    }

    // conv1 weight fragments: c1wf[s][off(4)][grp][c][8], use off 0..1
    short8 wf1[5][2];
#pragma unroll
    for (int s = 0; s < 5; s++)
#pragma unroll
        for (int off = 0; off < 2; off++)
            wf1[s][off] = *(const short8*)&c1wf[(((s * 4 + off) * 4 + grp) * 16 + c) * 8];
    int ciA[5], kpA[5];
#pragma unroll
    for (int s = 0; s < 5; s++) {
        int b = s * 4 + grp; if (b > 17) b = 17;   // clamped dup has zero weights
        ciA[s] = b / 6; kpA[s] = b % 6;
    }
    const float bias1 = (c < 6) ? c1b[c] : 0.f;

    const float4* xs4 = (const float4*)(x + (size_t)blockIdx.x * 49152);
    float4 r[6];

    // prologue: load subtile 0 (2 samples = 1536 float4)
#pragma unroll
    for (int k = 0; k < 6; k++) r[k] = xs4[k * 256 + t];

    for (int st = 0; st < 8; st++) {
        // convert + ds_write current subtile (1x per element)
#pragma unroll
        for (int k = 0; k < 6; k++) {
            int f = k * 256 + t;                  // 0..1535
            int s = (f >= 768) ? 1 : 0;
            int w4 = f - s * 768;
            int ci = w4 >> 8, rem = w4 & 255, y = rem >> 3, xq = rem & 7;
            us4v pk = { f2bf(r[k].x), f2bf(r[k].y), f2bf(r[k].z), f2bf(r[k].w) };
            *(us4v*)&img[s * C1T_SS + (ci * 32 + y) * C1_RS + xq * 4] = pk;
        }
        __syncthreads();

        // issue next subtile's loads (fly under this subtile's compute)
        if (st < 7) {
#pragma unroll
            for (int k = 0; k < 6; k++) r[k] = xs4[(st + 1) * 1536 + k * 256 + t];
        }

        // conv1 compute: 14 py items over 4 waves
        for (int py = w; py < 14; py += 4) {
            f32x4 a00 = {0.f,0.f,0.f,0.f}, a01 = a00, a10 = a00, a11 = a00;
#pragma unroll
            for (int s = 0; s < 5; s++) {
                int e = smp * C1T_SS + (ciA[s] * 32 + py * 2 + kpA[s]) * C1_RS + q * 4;
                us4v h0 = *(const us4v*)&img[e];
                us4v h1 = *(const us4v*)&img[e + 4];
                ushort2 h2 = *(const ushort2*)&img[e + 8];
                short8 A0 = { (short)h0[0],(short)h0[1],(short)h0[2],(short)h0[3],
                              (short)h1[0],(short)h1[1],(short)h1[2],(short)h1[3] };
                short8 A2 = { (short)h0[2],(short)h0[3],(short)h1[0],(short)h1[1],
                              (short)h1[2],(short)h1[3],(short)h2.x,(short)h2.y };
                a00 = __builtin_amdgcn_mfma_f32_16x16x32_bf16(A0, wf1[s][0], a00, 0, 0, 0);
                a01 = __builtin_amdgcn_mfma_f32_16x16x32_bf16(A0, wf1[s][1], a01, 0, 0, 0);
                a10 = __builtin_amdgcn_mfma_f32_16x16x32_bf16(A2, wf1[s][0], a10, 0, 0, 0);
                a11 = __builtin_amdgcn_mfma_f32_16x16x32_bf16(A2, wf1[s][1], a11, 0, 0, 0);
            }
            // pool x-pairs in-lane, y-pair across lane c <-> c+8
            f32x4 pe, po, pe2, po2;
#pragma unroll
            for (int i = 0; i < 4; i++) {
                pe[i] = fmaxf(a00[i], a01[i]);
                po[i] = fmaxf(a10[i], a11[i]);
            }
#pragma unroll
            for (int i = 0; i < 4; i++) {
                pe2[i] = fmaxf(pe[i], __shfl_xor(pe[i], 8));
                po2[i] = fmaxf(po[i], __shfl_xor(po[i], 8));
            }
            if (c < 6) {
#pragma unroll
                for (int i = 0; i < 4; i++) {
                    int m = grp * 4 + i;           // D row: sample = m>>3, quad = m&7
                    int qo = m & 7;
                    if (qo < 7) {
                        int sm = m >> 3;
                        float v0 = fmaxf(pe2[i] + bias1, 0.f);
                        float v1 = fmaxf(po2[i] + bias1, 0.f);
                        unsigned pk = (unsigned)f2bf(v0) | ((unsigned)f2bf(v1) << 16);
                        *(unsigned*)&p1s[(2 * st + sm) * P1R + (c * 14 + py) * 14 + qo * 2] = pk;
                    }
                }
            }
        }
        __syncthreads();   // img reads done before next convert; p1s subtile written
    }

    // ---- conv2 phase (wf2 loaded after conv1 regs die) ----
    short8 wf2[8][2];
#pragma unroll
    for (int s = 0; s < 8; s++)
#pragma unroll
        for (int off = 0; off < 2; off++)
            wf2[s][off] = *(const short8*)&c2wf[(((s * 2 + off) * 4 + grp) * 16 + c) * 8];
    int ciB[8], kyB[8];
#pragma unroll
    for (int s = 0; s < 8; s++) {
        int b = s * 4 + grp; if (b > 29) b = 29;   // clamped dup has zero weights
        ciB[s] = b / 5; kyB[s] = b % 5;
    }
    const float bias2 = c2b[c];

    for (int item = w; item < 25; item += 4) {
        int py = item / 5, px = item % 5;
        f32x4 a00 = {0.f,0.f,0.f,0.f}, a01 = a00, a10 = a00, a11 = a00;
#pragma unroll
        for (int s = 0; s < 8; s++) {
            int rbase = ciB[s] * 14 + kyB[s] + py * 2;
#pragma unroll
            for (int yo = 0; yo < 2; yo++) {
                int e = c * P1R + (rbase + yo) * 14 + px * 2;
                union { unsigned u[4]; short8 v; } af;
                af.u[0] = *(const unsigned*)&p1s[e];
                af.u[1] = *(const unsigned*)&p1s[e + 2];
                af.u[2] = *(const unsigned*)&p1s[e + 4];
                af.u[3] = *(const unsigned*)&p1s[e + 6];
                if (yo == 0) {
                    a00 = __builtin_amdgcn_mfma_f32_16x16x32_bf16(af.v, wf2[s][0], a00, 0, 0, 0);
                    a01 = __builtin_amdgcn_mfma_f32_16x16x32_bf16(af.v, wf2[s][1], a01, 0, 0, 0);
                } else {
                    a10 = __builtin_amdgcn_mfma_f32_16x16x32_bf16(af.v, wf2[s][0], a10, 0, 0, 0);
                    a11 = __builtin_amdgcn_mfma_f32_16x16x32_bf16(af.v, wf2[s][1], a11, 0, 0, 0);
                }
            }
        }
#pragma unroll
        for (int i = 0; i < 4; i++) {
            float mx = fmaxf(fmaxf(a00[i], a01[i]), fmaxf(a10[i], a11[i]));
            float v = fmaxf(mx + bias2, 0.f);
            int n = blockIdx.x * 16 + grp * 4 + i;
            P2[(size_t)n * 400 + c * 25 + py * 5 + px] = f2bf(v);
        }
    }
}

// one-shot conversion: FC weights to padded bf16 tiles + conv weight fragments
__global__ __launch_bounds__(256) void prep_weights(
    const float* __restrict__ c1w, const float* __restrict__ c2w,
    const float* __restrict__ f1w, const float* __restrict__ f2w,
    const float* __restrict__ f3w,
    unsigned short* __restrict__ wb1, unsigned short* __restrict__ wb2,
    unsigned short* __restrict__ wb3,
    unsigned short* __restrict__ c1wf, unsigned short* __restrict__ c2wf)
{
    const int t0 = blockIdx.x * 256 + threadIdx.x;
    const int stride = gridDim.x * 256;
    for (int i = t0; i < 128 * 416; i += stride) {
        int o = i / 416, k = i % 416;
        wb1[i] = f2bf((o < 120 && k < 400) ? f1w[o * 400 + k] : 0.f);
    }
    for (int i = t0; i < 96 * 128; i += stride) {
        int o = i / 128, k = i % 128;
        wb2[i] = f2bf((o < 84 && k < 120) ? f2w[o * 120 + k] : 0.f);
    }
    for (int i = t0; i < 64 * 96; i += stride) {
        int o = i / 96, k = i % 96;
        wb3[i] = f2bf((k < 84) ? f3w[o * 84 + k] : 0.f);
    }
    // c1wf[s(5)][off(4)][grp(4)][c(16)][j(8)]
    for (int i = t0; i < 10240; i += stride) {
        int j = i & 7, c = (i >> 3) & 15, grp = (i >> 7) & 3;
        int off = (i >> 9) & 3, s = i >> 11;
        int b = s * 4 + grp;
        int ci = b / 6, kp = b % 6;
        int kx = j - off;
        float v = 0.f;
        if (b < 18 && kx >= 0 && kx <= 4) {
            if (c < 6 && kp <= 4)
                v = c1w[c * 75 + ci * 25 + kp * 5 + kx];
            else if (c >= 8 && c < 14 && kp >= 1)
                v = c1w[(c - 8) * 75 + ci * 25 + (kp - 1) * 5 + kx];
        }
        c1wf[i] = f2bf(v);
    }
    // c2wf[s(8)][off(2)][grp(4)][c(16)][j(8)]
    for (int i = t0; i < 8192; i += stride) {
        int j = i & 7, c = (i >> 3) & 15, grp = (i >> 7) & 3;
        int off = (i >> 9) & 1, s = i >> 10;
        int b = s * 4 + grp;
        int kx = j - off;
        float v = 0.f;
        if (b < 30 && kx >= 0 && kx <= 4) {
            int ci = b / 5, ky = b % 5;
            v = c2w[c * 150 + ci * 25 + ky * 5 + kx];
        }
        c2wf[i] = f2bf(v);
    }
}

#define FCS 32
#define P2S 424
#define A1S 136
#define A2S 104

// FC1->FC2->FC3 via bf16 MFMA
__global__ __launch_bounds__(256, 3) void fc_mfma(
    const unsigned short* __restrict__ P2,
    const unsigned short* __restrict__ wb1, const float* __restrict__ f1b,
    const unsigned short* __restrict__ wb2, const float* __restrict__ f2b,
    const unsigned short* __restrict__ wb3, const float* __restrict__ f3b,
    float* __restrict__ emb)
{
    __shared__ __align__(16) unsigned short p2s[FCS * P2S];
    __shared__ __align__(16) unsigned short a1s[FCS * A1S];
    __shared__ __align__(16) unsigned short a2s[FCS * A2S];
    const int t = threadIdx.x, lane = t & 63, w = t >> 6;
    const int grp = lane >> 4, c = lane & 15;

    if (t < 64) {
        int s = t >> 1, h = t & 1;
        *(uint4*)&p2s[s * P2S + 400 + h * 8] = make_uint4(0u, 0u, 0u, 0u);
    }
    const uint4* src = (const uint4*)(P2 + (size_t)blockIdx.x * FCS * 400);
    for (int i = t; i < FCS * 50; i += 256) {
        int s = i / 50, k8 = i % 50;
        *(uint4*)&p2s[s * P2S + k8 * 8] = src[i];
    }
    __syncthreads();

    const int m = w & 1;
    const int arow = m * 16 + c;

    {
        const int n0 = (w >> 1) * 4;
        f32x4 acc[4] = {{0.f,0.f,0.f,0.f},{0.f,0.f,0.f,0.f},{0.f,0.f,0.f,0.f},{0.f,0.f,0.f,0.f}};
        const int sb = arow * P2S;
#pragma unroll
        for (int ks = 0; ks < 13; ks++) {
            short8 a = *(const short8*)&p2s[sb + ks * 32 + grp * 8];
#pragma unroll
            for (int j = 0; j < 4; j++) {
                int o = (n0 + j) * 16 + c;
                short8 b = *(const short8*)&wb1[o * 416 + ks * 32 + grp * 8];
                acc[j] = __builtin_amdgcn_mfma_f32_16x16x32_bf16(a, b, acc[j], 0, 0, 0);
            }
        }
#pragma unroll
        for (int j = 0; j < 4; j++) {
            int o = (n0 + j) * 16 + c;
            float bias = (o < 120) ? f1b[o] : 0.f;
#pragma unroll
            for (int i = 0; i < 4; i++) {
                int s = m * 16 + grp * 4 + i;
                a1s[s * A1S + o] = f2bf(fmaxf(acc[j][i] + bias, 0.f));
            }
        }
    }
    __syncthreads();

    {
        const int n0 = (w >> 1) * 3;
        f32x4 acc[3] = {{0.f,0.f,0.f,0.f},{0.f,0.f,0.f,0.f},{0.f,0.f,0.f,0.f}};
        const int sb = arow * A1S;
#pragma unroll
        for (int ks = 0; ks < 4; ks++) {
            short8 a = *(const short8*)&a1s[sb + ks * 32 + grp * 8];
#pragma unroll
            for (int j = 0; j < 3; j++) {
                int o = (n0 + j) * 16 + c;
                short8 b = *(const short8*)&wb2[o * 128 + ks * 32 + grp * 8];
                acc[j] = __builtin_amdgcn_mfma_f32_16x16x32_bf16(a, b, acc[j], 0, 0, 0);
            }
        }
#pragma unroll
        for (int j = 0; j < 3; j++) {
            int o = (n0 + j) * 16 + c;
            float bias = (o < 84) ? f2b[o] : 0.f;
#pragma unroll
            for (int i = 0; i < 4; i++) {
                int s = m * 16 + grp * 4 + i;
                a2s[s * A2S + o] = f2bf(fmaxf(acc[j][i] + bias, 0.f));
            }
        }
    }
    __syncthreads();

    {
        const int n0 = (w >> 1) * 2;
        f32x4 acc[2] = {{0.f,0.f,0.f,0.f},{0.f,0.f,0.f,0.f}};
        const int sb = arow * A2S;
#pragma unroll
        for (int ks = 0; ks < 3; ks++) {
            short8 a = *(const short8*)&a2s[sb + ks * 32 + grp * 8];
#pragma unroll
            for (int j = 0; j < 2; j++) {
                int o = (n0 + j) * 16 + c;
                short8 b = *(const short8*)&wb3[o * 96 + ks * 32 + grp * 8];
                acc[j] = __builtin_amdgcn_mfma_f32_16x16x32_bf16(a, b, acc[j], 0, 0, 0);
            }
        }
#pragma unroll
        for (int j = 0; j < 2; j++) {
            int o = (n0 + j) * 16 + c;
            float bias = f3b[o];
#pragma unroll
            for (int i = 0; i < 4; i++) {
                int s = m * 16 + grp * 4 + i;
                emb[((size_t)blockIdx.x * FCS + s) * 64 + o] = acc[j][i] + bias;
            }
        }
    }
}

__global__ __launch_bounds__(256) void reduce_emb(const float* __restrict__ emb,
                                                  float* __restrict__ part, int total) {
    __shared__ float s_[256];
    const int t = threadIdx.x;
    const int chunk = total / 256;
    const float* base = emb + (size_t)blockIdx.x * chunk;
    float s = 0.f;
    for (int j = t; j < chunk; j += 256) s += base[j];
    s_[t] = s; __syncthreads();
    for (int off = 128; off > 0; off >>= 1) {
        if (t < off) s_[t] += s_[t + off];
        __syncthreads();
    }
    if (t == 0) part[blockIdx.x] = s_[0];
}

__global__ __launch_bounds__(256) void reduce_part(const float* __restrict__ part,
                                                   float* __restrict__ proto) {
    __shared__ float s_[256];
    const int t = threadIdx.x;
    s_[t] = part[t]; __syncthreads();
    for (int off = 128; off > 0; off >>= 1) {
        if (t < off) s_[t] += s_[t + off];
        __syncthreads();
    }
    if (t == 0) proto[0] = s_[0] / 5.0f;
}

__global__ __launch_bounds__(256) void softmax_abs(float* __restrict__ io,
                                                   const float* __restrict__ proto_p) {
    const int lane = threadIdx.x & 63;
    const int row = (blockIdx.x << 2) + (threadIdx.x >> 6);
    const float proto = proto_p[0];
    float e = io[(size_t)row * 64 + lane];
    float m = e;
#pragma unroll
    for (int off = 32; off; off >>= 1) m = fmaxf(m, __shfl_xor(m, off));
    float p = expf(e - m);
    float s = p;
#pragma unroll
    for (int off = 32; off; off >>= 1) s += __shfl_xor(s, off);
    io[(size_t)row * 64 + lane] = fabsf(p / s - proto);
}

extern "C" void kernel_launch(void* const* d_in, const int* in_sizes, int n_in,
                              void* d_out, int out_size, void* d_ws, size_t ws_size,
                              hipStream_t stream) {
    const float* x   = (const float*)d_in[0];
    const float* c1w = (const float*)d_in[1];
    const float* c1b = (const float*)d_in[2];
    const float* c2w = (const float*)d_in[3];
    const float* c2b = (const float*)d_in[4];
    const float* f1w = (const float*)d_in[5];
    const float* f1b = (const float*)d_in[6];
    const float* f2w = (const float*)d_in[7];
    const float* f2b = (const float*)d_in[8];
    const float* f3w = (const float*)d_in[9];
    const float* f3b = (const float*)d_in[10];
    float* out = (float*)d_out;

    const int N = in_sizes[0] / 3072;                 // 20480
    const size_t p2_bytes = (size_t)N * 400 * 2;      // 16.4 MB
    unsigned short* P2 = (unsigned short*)d_ws;
    char* tail = (char*)d_ws + p2_bytes;
    float* part  = (float*)tail;                      // 256 floats
    float* proto = part + 256;                        // 1 float
    unsigned short* wb1  = (unsigned short*)(tail + 2048);  // 128x416
    unsigned short* wb2  = wb1 + 128 * 416;                 // 96x128
    unsigned short* wb3  = wb2 + 96 * 128;                  // 64x96
    unsigned short* c1wf = wb3 + 64 * 96;                   // 10240
    unsigned short* c2wf = c1wf + 10240;                    // 8192

    prep_weights<<<64, 256, 0, stream>>>(c1w, c2w, f1w, f2w, f3w,
                                         wb1, wb2, wb3, c1wf, c2wf);
    conv12_mfma<<<N / 16, 256, 0, stream>>>(x, c1wf, c1b, c2wf, c2b, P2);
    fc_mfma<<<N / 32, 256, 0, stream>>>(P2, wb1, f1b, wb2, f2b, wb3, f3b, out);
    reduce_emb<<<256, 256, 0, stream>>>(out, part, N * 64);
    reduce_part<<<1, 256, 0, stream>>>(part, proto);
    softmax_abs<<<N / 4, 256, 0, stream>>>(out, proto);
}

// Round 11
// 123.196 us; speedup vs baseline: 1.4295x; 1.0519x over previous
//
#include <hip/hip_runtime.h>
#include <math.h>

typedef __attribute__((ext_vector_type(8))) short short8;
typedef __attribute__((ext_vector_type(4))) float f32x4;
typedef __attribute__((ext_vector_type(4))) unsigned short us4v;

__device__ __forceinline__ unsigned short f2bf(float f) {
    unsigned u = __float_as_uint(f);
    return (unsigned short)((u + 0x7FFFu + ((u >> 16) & 1u)) >> 16);
}
// HW packed f32->bf16 (RNE, same as f2bf): 2 elems in 1 instr
__device__ __forceinline__ unsigned cvtpk(float lo, float hi) {
    unsigned r;
    asm("v_cvt_pk_bf16_f32 %0, %1, %2" : "=v"(r) : "v"(lo), "v"(hi));
    return r;
}
__device__ __forceinline__ unsigned short f2bf1(float v) {
    return (unsigned short)(cvtpk(v, 0.f) & 0xffffu);
}
// max with lane (c <-> c+8) partner via DPP row_ror:8 — VALU-only, no LDS pipe
__device__ __forceinline__ float fmax_x8(float v) {
    int s = __builtin_amdgcn_mov_dpp(__float_as_int(v), 0x128, 0xf, 0xf, true);
    return fmaxf(v, __int_as_float(s));
}

#define C1T_SS 3464  // conv1 img LDS elems per sample (96 rows x 36 + 8 tail)
#define C1_RS 36     // conv1 img LDS row stride (32 data + 4 pad)
#define P1R 1176     // p1 record per sample: 84 rows x 14 (stride 14)

// Fused conv1+pool -> conv2+pool via bf16 MFMA. 16 samples/block.
// conv1: 8 register-pipelined 2-sample subtiles, pooled output written
// DIRECTLY to LDS p1s (conv2's consumption layout). This round: staging
// conversion via v_cvt_pk_bf16_f32 (4x fewer VALU) and pool reduce via
// DPP row_ror:8 (kills 8 ds_bpermute per py-item).
__global__ __launch_bounds__(256, 3) void conv12_mfma(
    const float* __restrict__ x,
    const unsigned short* __restrict__ c1wf, const float* __restrict__ c1b,
    const unsigned short* __restrict__ c2wf, const float* __restrict__ c2b,
    unsigned short* __restrict__ P2)
{
    __shared__ __align__(16) unsigned short img[2 * C1T_SS];    // 13856 B
    __shared__ __align__(16) unsigned short p1s[16 * P1R + 16]; // 37664 B
    const int t = threadIdx.x;
    const int lane = t & 63, w = t >> 6;
    const int grp = lane >> 4, c = lane & 15;
    const int smp = c >> 3, q = c & 7;

    // zero img row pads (2x96 rows, elems 32..35) + sample tails + p1s tail pad
    if (t < 192) {
        int s = t / 96, rr = t - s * 96;
        *(uint2*)&img[s * C1T_SS + rr * C1_RS + 32] = make_uint2(0u, 0u);
    }
    if (t < 2) {
        *(uint4*)&img[t * C1T_SS + 3456] = make_uint4(0u, 0u, 0u, 0u);
        *(uint4*)&p1s[16 * P1R + t * 8] = make_uint4(0u, 0u, 0u, 0u);
    }

    // conv1 weight fragments: c1wf[s][off(4)][grp][c][8], use off 0..1
    short8 wf1[5][2];
#pragma unroll
    for (int s = 0; s < 5; s++)
#pragma unroll
        for (int off = 0; off < 2; off++)
            wf1[s][off] = *(const short8*)&c1wf[(((s * 4 + off) * 4 + grp) * 16 + c) * 8];
    int ciA[5], kpA[5];
#pragma unroll
    for (int s = 0; s < 5; s++) {
        int b = s * 4 + grp; if (b > 17) b = 17;   // clamped dup has zero weights
        ciA[s] = b / 6; kpA[s] = b % 6;
    }
    const float bias1 = (c < 6) ? c1b[c] : 0.f;

    const float4* xs4 = (const float4*)(x + (size_t)blockIdx.x * 49152);
    float4 r[6];

    // prologue: load subtile 0 (2 samples = 1536 float4)
#pragma unroll
    for (int k = 0; k < 6; k++) r[k] = xs4[k * 256 + t];

    for (int st = 0; st < 8; st++) {
        // convert + ds_write current subtile (1x per element, cvt_pk)
#pragma unroll
        for (int k = 0; k < 6; k++) {
            int f = k * 256 + t;                  // 0..1535
            int s = (f >= 768) ? 1 : 0;
            int w4 = f - s * 768;
            int ci = w4 >> 8, rem = w4 & 255, y = rem >> 3, xq = rem & 7;
            uint2 pk = make_uint2(cvtpk(r[k].x, r[k].y), cvtpk(r[k].z, r[k].w));
            *(uint2*)&img[s * C1T_SS + (ci * 32 + y) * C1_RS + xq * 4] = pk;
        }
        __syncthreads();

        // issue next subtile's loads (fly under this subtile's compute)
        if (st < 7) {
#pragma unroll
            for (int k = 0; k < 6; k++) r[k] = xs4[(st + 1) * 1536 + k * 256 + t];
        }

        // conv1 compute: 14 py items over 4 waves
        for (int py = w; py < 14; py += 4) {
            f32x4 a00 = {0.f,0.f,0.f,0.f}, a01 = a00, a10 = a00, a11 = a00;
#pragma unroll
            for (int s = 0; s < 5; s++) {
                int e = smp * C1T_SS + (ciA[s] * 32 + py * 2 + kpA[s]) * C1_RS + q * 4;
                us4v h0 = *(const us4v*)&img[e];
                us4v h1 = *(const us4v*)&img[e + 4];
                ushort2 h2 = *(const ushort2*)&img[e + 8];
                short8 A0 = { (short)h0[0],(short)h0[1],(short)h0[2],(short)h0[3],
                              (short)h1[0],(short)h1[1],(short)h1[2],(short)h1[3] };
                short8 A2 = { (short)h0[2],(short)h0[3],(short)h1[0],(short)h1[1],
                              (short)h1[2],(short)h1[3],(short)h2.x,(short)h2.y };
                a00 = __builtin_amdgcn_mfma_f32_16x16x32_bf16(A0, wf1[s][0], a00, 0, 0, 0);
                a01 = __builtin_amdgcn_mfma_f32_16x16x32_bf16(A0, wf1[s][1], a01, 0, 0, 0);
                a10 = __builtin_amdgcn_mfma_f32_16x16x32_bf16(A2, wf1[s][0], a10, 0, 0, 0);
                a11 = __builtin_amdgcn_mfma_f32_16x16x32_bf16(A2, wf1[s][1], a11, 0, 0, 0);
            }
            // pool x-pairs in-lane, y-pair across lane c <-> c+8 (DPP, no LDS)
            f32x4 pe2, po2;
#pragma unroll
            for (int i = 0; i < 4; i++) {
                pe2[i] = fmax_x8(fmaxf(a00[i], a01[i]));
                po2[i] = fmax_x8(fmaxf(a10[i], a11[i]));
            }
            if (c < 6) {
#pragma unroll
                for (int i = 0; i < 4; i++) {
                    int m = grp * 4 + i;           // D row: sample = m>>3, quad = m&7
                    int qo = m & 7;
                    if (qo < 7) {
                        int sm = m >> 3;
                        float v0 = fmaxf(pe2[i] + bias1, 0.f);
                        float v1 = fmaxf(po2[i] + bias1, 0.f);
                        *(unsigned*)&p1s[(2 * st + sm) * P1R + (c * 14 + py) * 14 + qo * 2]
                            = cvtpk(v0, v1);
                    }
                }
            }
        }
        __syncthreads();   // img reads done before next convert; p1s subtile written
    }

    // ---- conv2 phase (wf2 loaded after conv1 regs die) ----
    short8 wf2[8][2];
#pragma unroll
    for (int s = 0; s < 8; s++)
#pragma unroll
        for (int off = 0; off < 2; off++)
            wf2[s][off] = *(const short8*)&c2wf[(((s * 2 + off) * 4 + grp) * 16 + c) * 8];
    int ciB[8], kyB[8];
#pragma unroll
    for (int s = 0; s < 8; s++) {
        int b = s * 4 + grp; if (b > 29) b = 29;   // clamped dup has zero weights
        ciB[s] = b / 5; kyB[s] = b % 5;
    }
    const float bias2 = c2b[c];

    for (int item = w; item < 25; item += 4) {
        int py = item / 5, px = item % 5;
        f32x4 a00 = {0.f,0.f,0.f,0.f}, a01 = a00, a10 = a00, a11 = a00;
#pragma unroll
        for (int s = 0; s < 8; s++) {
            int rbase = ciB[s] * 14 + kyB[s] + py * 2;
#pragma unroll
            for (int yo = 0; yo < 2; yo++) {
                int e = c * P1R + (rbase + yo) * 14 + px * 2;
                union { unsigned u[4]; short8 v; } af;
                af.u[0] = *(const unsigned*)&p1s[e];
                af.u[1] = *(const unsigned*)&p1s[e + 2];
                af.u[2] = *(const unsigned*)&p1s[e + 4];
                af.u[3] = *(const unsigned*)&p1s[e + 6];
                if (yo == 0) {
                    a00 = __builtin_amdgcn_mfma_f32_16x16x32_bf16(af.v, wf2[s][0], a00, 0, 0, 0);
                    a01 = __builtin_amdgcn_mfma_f32_16x16x32_bf16(af.v, wf2[s][1], a01, 0, 0, 0);
                } else {
                    a10 = __builtin_amdgcn_mfma_f32_16x16x32_bf16(af.v, wf2[s][0], a10, 0, 0, 0);
                    a11 = __builtin_amdgcn_mfma_f32_16x16x32_bf16(af.v, wf2[s][1], a11, 0, 0, 0);
                }
            }
        }
#pragma unroll
        for (int i = 0; i < 4; i++) {
            float mx = fmaxf(fmaxf(a00[i], a01[i]), fmaxf(a10[i], a11[i]));
            float v = fmaxf(mx + bias2, 0.f);
            int n = blockIdx.x * 16 + grp * 4 + i;
            P2[(size_t)n * 400 + c * 25 + py * 5 + px] = f2bf1(v);
        }
    }
}

// one-shot conversion: FC weights to padded bf16 tiles + conv weight fragments
__global__ __launch_bounds__(256) void prep_weights(
    const float* __restrict__ c1w, const float* __restrict__ c2w,
    const float* __restrict__ f1w, const float* __restrict__ f2w,
    const float* __restrict__ f3w,
    unsigned short* __restrict__ wb1, unsigned short* __restrict__ wb2,
    unsigned short* __restrict__ wb3,
    unsigned short* __restrict__ c1wf, unsigned short* __restrict__ c2wf)
{
    const int t0 = blockIdx.x * 256 + threadIdx.x;
    const int stride = gridDim.x * 256;
    for (int i = t0; i < 128 * 416; i += stride) {
        int o = i / 416, k = i % 416;
        wb1[i] = f2bf((o < 120 && k < 400) ? f1w[o * 400 + k] : 0.f);
    }
    for (int i = t0; i < 96 * 128; i += stride) {
        int o = i / 128, k = i % 128;
        wb2[i] = f2bf((o < 84 && k < 120) ? f2w[o * 120 + k] : 0.f);
    }
    for (int i = t0; i < 64 * 96; i += stride) {
        int o = i / 96, k = i % 96;
        wb3[i] = f2bf((k < 84) ? f3w[o * 84 + k] : 0.f);
    }
    // c1wf[s(5)][off(4)][grp(4)][c(16)][j(8)]
    for (int i = t0; i < 10240; i += stride) {
        int j = i & 7, c = (i >> 3) & 15, grp = (i >> 7) & 3;
        int off = (i >> 9) & 3, s = i >> 11;
        int b = s * 4 + grp;
        int ci = b / 6, kp = b % 6;
        int kx = j - off;
        float v = 0.f;
        if (b < 18 && kx >= 0 && kx <= 4) {
            if (c < 6 && kp <= 4)
                v = c1w[c * 75 + ci * 25 + kp * 5 + kx];
            else if (c >= 8 && c < 14 && kp >= 1)
                v = c1w[(c - 8) * 75 + ci * 25 + (kp - 1) * 5 + kx];
        }
        c1wf[i] = f2bf(v);
    }
    // c2wf[s(8)][off(2)][grp(4)][c(16)][j(8)]
    for (int i = t0; i < 8192; i += stride) {
        int j = i & 7, c = (i >> 3) & 15, grp = (i >> 7) & 3;
        int off = (i >> 9) & 1, s = i >> 10;
        int b = s * 4 + grp;
        int kx = j - off;
        float v = 0.f;
        if (b < 30 && kx >= 0 && kx <= 4) {
            int ci = b / 5, ky = b % 5;
            v = c2w[c * 150 + ci * 25 + ky * 5 + kx];
        }
        c2wf[i] = f2bf(v);
    }
}

#define FCS 32
#define P2S 424
#define A1S 136
#define A2S 104

// FC1->FC2->FC3 via bf16 MFMA
__global__ __launch_bounds__(256, 3) void fc_mfma(
    const unsigned short* __restrict__ P2,
    const unsigned short* __restrict__ wb1, const float* __restrict__ f1b,
    const unsigned short* __restrict__ wb2, const float* __restrict__ f2b,
    const unsigned short* __restrict__ wb3, const float* __restrict__ f3b,
    float* __restrict__ emb)
{
    __shared__ __align__(16) unsigned short p2s[FCS * P2S];
    __shared__ __align__(16) unsigned short a1s[FCS * A1S];
    __shared__ __align__(16) unsigned short a2s[FCS * A2S];
    const int t = threadIdx.x, lane = t & 63, w = t >> 6;
    const int grp = lane >> 4, c = lane & 15;

    if (t < 64) {
        int s = t >> 1, h = t & 1;
        *(uint4*)&p2s[s * P2S + 400 + h * 8] = make_uint4(0u, 0u, 0u, 0u);
    }
    const uint4* src = (const uint4*)(P2 + (size_t)blockIdx.x * FCS * 400);
    for (int i = t; i < FCS * 50; i += 256) {
        int s = i / 50, k8 = i % 50;
        *(uint4*)&p2s[s * P2S + k8 * 8] = src[i];
    }
    __syncthreads();

    const int m = w & 1;
    const int arow = m * 16 + c;

    {
        const int n0 = (w >> 1) * 4;
        f32x4 acc[4] = {{0.f,0.f,0.f,0.f},{0.f,0.f,0.f,0.f},{0.f,0.f,0.f,0.f},{0.f,0.f,0.f,0.f}};
        const int sb = arow * P2S;
#pragma unroll
        for (int ks = 0; ks < 13; ks++) {
            short8 a = *(const short8*)&p2s[sb + ks * 32 + grp * 8];
#pragma unroll
            for (int j = 0; j < 4; j++) {
                int o = (n0 + j) * 16 + c;
                short8 b = *(const short8*)&wb1[o * 416 + ks * 32 + grp * 8];
                acc[j] = __builtin_amdgcn_mfma_f32_16x16x32_bf16(a, b, acc[j], 0, 0, 0);
            }
        }
#pragma unroll
        for (int j = 0; j < 4; j++) {
            int o = (n0 + j) * 16 + c;
            float bias = (o < 120) ? f1b[o] : 0.f;
#pragma unroll
            for (int i = 0; i < 4; i++) {
                int s = m * 16 + grp * 4 + i;
                a1s[s * A1S + o] = f2bf1(fmaxf(acc[j][i] + bias, 0.f));
            }
        }
    }
    __syncthreads();

    {
        const int n0 = (w >> 1) * 3;
        f32x4 acc[3] = {{0.f,0.f,0.f,0.f},{0.f,0.f,0.f,0.f},{0.f,0.f,0.f,0.f}};
        const int sb = arow * A1S;
#pragma unroll
        for (int ks = 0; ks < 4; ks++) {
            short8 a = *(const short8*)&a1s[sb + ks * 32 + grp * 8];
#pragma unroll
            for (int j = 0; j < 3; j++) {
                int o = (n0 + j) * 16 + c;
                short8 b = *(const short8*)&wb2[o * 128 + ks * 32 + grp * 8];
                acc[j] = __builtin_amdgcn_mfma_f32_16x16x32_bf16(a, b, acc[j], 0, 0, 0);
            }
        }
#pragma unroll
        for (int j = 0; j < 3; j++) {
            int o = (n0 + j) * 16 + c;
            float bias = (o < 84) ? f2b[o] : 0.f;
#pragma unroll
            for (int i = 0; i < 4; i++) {
                int s = m * 16 + grp * 4 + i;
                a2s[s * A2S + o] = f2bf1(fmaxf(acc[j][i] + bias, 0.f));
            }
        }
    }
    __syncthreads();

    {
        const int n0 = (w >> 1) * 2;
        f32x4 acc[2] = {{0.f,0.f,0.f,0.f},{0.f,0.f,0.f,0.f}};
        const int sb = arow * A2S;
#pragma unroll
        for (int ks = 0; ks < 3; ks++) {
            short8 a = *(const short8*)&a2s[sb + ks * 32 + grp * 8];
#pragma unroll
            for (int j = 0; j < 2; j++) {
                int o = (n0 + j) * 16 + c;
                short8 b = *(const short8*)&wb3[o * 96 + ks * 32 + grp * 8];
                acc[j] = __builtin_amdgcn_mfma_f32_16x16x32_bf16(a, b, acc[j], 0, 0, 0);
            }
        }
#pragma unroll
        for (int j = 0; j < 2; j++) {
            int o = (n0 + j) * 16 + c;
            float bias = f3b[o];
#pragma unroll
            for (int i = 0; i < 4; i++) {
                int s = m * 16 + grp * 4 + i;
                emb[((size_t)blockIdx.x * FCS + s) * 64 + o] = acc[j][i] + bias;
            }
        }
    }
}

__global__ __launch_bounds__(256) void reduce_emb(const float* __restrict__ emb,
                                                  float* __restrict__ part, int total) {
    __shared__ float s_[256];
    const int t = threadIdx.x;
    const int chunk = total / 256;
    const float* base = emb + (size_t)blockIdx.x * chunk;
    float s = 0.f;
    for (int j = t; j < chunk; j += 256) s += base[j];
    s_[t] = s; __syncthreads();
    for (int off = 128; off > 0; off >>= 1) {
        if (t < off) s_[t] += s_[t + off];
        __syncthreads();
    }
    if (t == 0) part[blockIdx.x] = s_[0];
}

__global__ __launch_bounds__(256) void reduce_part(const float* __restrict__ part,
                                                   float* __restrict__ proto) {
    __shared__ float s_[256];
    const int t = threadIdx.x;
    s_[t] = part[t]; __syncthreads();
    for (int off = 128; off > 0; off >>= 1) {
        if (t < off) s_[t] += s_[t + off];
        __syncthreads();
    }
    if (t == 0) proto[0] = s_[0] / 5.0f;
}

__global__ __launch_bounds__(256) void softmax_abs(float* __restrict__ io,
                                                   const float* __restrict__ proto_p) {
    const int lane = threadIdx.x & 63;
    const int row = (blockIdx.x << 2) + (threadIdx.x >> 6);
    const float proto = proto_p[0];
    float e = io[(size_t)row * 64 + lane];
    float m = e;
#pragma unroll
    for (int off = 32; off; off >>= 1) m = fmaxf(m, __shfl_xor(m, off));
    float p = expf(e - m);
    float s = p;
#pragma unroll
    for (int off = 32; off; off >>= 1) s += __shfl_xor(s, off);
    io[(size_t)row * 64 + lane] = fabsf(p / s - proto);
}

extern "C" void kernel_launch(void* const* d_in, const int* in_sizes, int n_in,
                              void* d_out, int out_size, void* d_ws, size_t ws_size,
                              hipStream_t stream) {
    const float* x   = (const float*)d_in[0];
    const float* c1w = (const float*)d_in[1];
    const float* c1b = (const float*)d_in[2];
    const float* c2w = (const float*)d_in[3];
    const float* c2b = (const float*)d_in[4];
    const float* f1w = (const float*)d_in[5];
    const float* f1b = (const float*)d_in[6];
    const float* f2w = (const float*)d_in[7];
    const float* f2b = (const float*)d_in[8];
    const float* f3w = (const float*)d_in[9];
    const float* f3b = (const float*)d_in[10];
    float* out = (float*)d_out;

    const int N = in_sizes[0] / 3072;                 // 20480
    const size_t p2_bytes = (size_t)N * 400 * 2;      // 16.4 MB
    unsigned short* P2 = (unsigned short*)d_ws;
    char* tail = (char*)d_ws + p2_bytes;
    float* part  = (float*)tail;                      // 256 floats
    float* proto = part + 256;                        // 1 float
    unsigned short* wb1  = (unsigned short*)(tail + 2048);  // 128x416
    unsigned short* wb2  = wb1 + 128 * 416;                 // 96x128
    unsigned short* wb3  = wb2 + 96 * 128;                  // 64x96
    unsigned short* c1wf = wb3 + 64 * 96;                   // 10240
    unsigned short* c2wf = c1wf + 10240;                    // 8192

    prep_weights<<<64, 256, 0, stream>>>(c1w, c2w, f1w, f2w, f3w,
                                         wb1, wb2, wb3, c1wf, c2wf);
    conv12_mfma<<<N / 16, 256, 0, stream>>>(x, c1wf, c1b, c2wf, c2b, P2);
    fc_mfma<<<N / 32, 256, 0, stream>>>(P2, wb1, f1b, wb2, f2b, wb3, f3b, out);
    reduce_emb<<<256, 256, 0, stream>>>(out, part, N * 64);
    reduce_part<<<1, 256, 0, stream>>>(part, proto);
    softmax_abs<<<N / 4, 256, 0, stream>>>(out, proto);
}

// Round 12
// 114.953 us; speedup vs baseline: 1.5320x; 1.0717x over previous
//
#include <hip/hip_runtime.h>
#include <math.h>

typedef __attribute__((ext_vector_type(8))) short short8;
typedef __attribute__((ext_vector_type(4))) float f32x4;
typedef __attribute__((ext_vector_type(4))) unsigned short us4v;

__device__ __forceinline__ unsigned short f2bf(float f) {
    unsigned u = __float_as_uint(f);
    return (unsigned short)((u + 0x7FFFu + ((u >> 16) & 1u)) >> 16);
}
// HW packed f32->bf16 (RNE, same as f2bf): 2 elems in 1 instr
__device__ __forceinline__ unsigned cvtpk(float lo, float hi) {
    unsigned r;
    asm("v_cvt_pk_bf16_f32 %0, %1, %2" : "=v"(r) : "v"(lo), "v"(hi));
    return r;
}
__device__ __forceinline__ unsigned short f2bf1(float v) {
    return (unsigned short)(cvtpk(v, 0.f) & 0xffffu);
}
// max with lane (c <-> c+8) partner via DPP row_ror:8 — VALU-only, no LDS pipe
__device__ __forceinline__ float fmax_x8(float v) {
    int s = __builtin_amdgcn_mov_dpp(__float_as_int(v), 0x128, 0xf, 0xf, true);
    return fmaxf(v, __int_as_float(s));
}

#define C1T_SS 3464  // conv1 img LDS elems per sample (96 rows x 36 + 8 tail)
#define C1_RS 36     // conv1 img LDS row stride (32 data + 4 pad)
#define P1R 1176     // p1 record per sample: 84 rows x 14 (stride 14)

// Fused conv1+pool -> conv2+pool via bf16 MFMA. 16 samples/block.
// conv1: 8 register-pipelined 2-sample subtiles, pooled output written
// DIRECTLY to LDS p1s. This round: all 4 weight x-offset variants live in
// registers (wf1[5][4]) so the A-operand is ONE aligned 16B row chunk
// (ds_read2_b64) — no shifted-A2 repack, 1/3 the conv1 DS traffic.
__global__ __launch_bounds__(256, 3) void conv12_mfma(
    const float* __restrict__ x,
    const unsigned short* __restrict__ c1wf, const float* __restrict__ c1b,
    const unsigned short* __restrict__ c2wf, const float* __restrict__ c2b,
    unsigned short* __restrict__ P2)
{
    __shared__ __align__(16) unsigned short img[2 * C1T_SS];    // 13856 B
    __shared__ __align__(16) unsigned short p1s[16 * P1R + 16]; // 37664 B
    const int t = threadIdx.x;
    const int lane = t & 63, w = t >> 6;
    const int grp = lane >> 4, c = lane & 15;
    const int smp = c >> 3, q = c & 7;

    // zero img row pads (2x96 rows, elems 32..35) + sample tails + p1s tail pad
    if (t < 192) {
        int s = t / 96, rr = t - s * 96;
        *(uint2*)&img[s * C1T_SS + rr * C1_RS + 32] = make_uint2(0u, 0u);
    }
    if (t < 2) {
        *(uint4*)&img[t * C1T_SS + 3456] = make_uint4(0u, 0u, 0u, 0u);
        *(uint4*)&p1s[16 * P1R + t * 8] = make_uint4(0u, 0u, 0u, 0u);
    }

    // conv1 weight fragments: ALL 4 x-offset variants
    short8 wf1[5][4];
#pragma unroll
    for (int s = 0; s < 5; s++)
#pragma unroll
        for (int off = 0; off < 4; off++)
            wf1[s][off] = *(const short8*)&c1wf[(((s * 4 + off) * 4 + grp) * 16 + c) * 8];
    int ciA[5], kpA[5];
#pragma unroll
    for (int s = 0; s < 5; s++) {
        int b = s * 4 + grp; if (b > 17) b = 17;   // clamped dup has zero weights
        ciA[s] = b / 6; kpA[s] = b % 6;
    }
    const float bias1 = (c < 6) ? c1b[c] : 0.f;

    const float4* xs4 = (const float4*)(x + (size_t)blockIdx.x * 49152);
    float4 r[6];

    // prologue: load subtile 0 (2 samples = 1536 float4)
#pragma unroll
    for (int k = 0; k < 6; k++) r[k] = xs4[k * 256 + t];

    for (int st = 0; st < 8; st++) {
        // convert + ds_write current subtile (1x per element, cvt_pk)
#pragma unroll
        for (int k = 0; k < 6; k++) {
            int f = k * 256 + t;                  // 0..1535
            int s = (f >= 768) ? 1 : 0;
            int w4 = f - s * 768;
            int ci = w4 >> 8, rem = w4 & 255, y = rem >> 3, xq = rem & 7;
            uint2 pk = make_uint2(cvtpk(r[k].x, r[k].y), cvtpk(r[k].z, r[k].w));
            *(uint2*)&img[s * C1T_SS + (ci * 32 + y) * C1_RS + xq * 4] = pk;
        }
        __syncthreads();

        // issue next subtile's loads (fly under this subtile's compute)
        if (st < 7) {
#pragma unroll
            for (int k = 0; k < 6; k++) r[k] = xs4[(st + 1) * 1536 + k * 256 + t];
        }

        // conv1 compute: 14 py items over 4 waves
        for (int py = w; py < 14; py += 4) {
            f32x4 a00 = {0.f,0.f,0.f,0.f}, a01 = a00, a10 = a00, a11 = a00;
#pragma unroll
            for (int s = 0; s < 5; s++) {
                int e = smp * C1T_SS + (ciA[s] * 32 + py * 2 + kpA[s]) * C1_RS + q * 4;
                union { us4v h[2]; short8 v; } af;
                af.h[0] = *(const us4v*)&img[e];
                af.h[1] = *(const us4v*)&img[e + 4];
                a00 = __builtin_amdgcn_mfma_f32_16x16x32_bf16(af.v, wf1[s][0], a00, 0, 0, 0);
                a01 = __builtin_amdgcn_mfma_f32_16x16x32_bf16(af.v, wf1[s][1], a01, 0, 0, 0);
                a10 = __builtin_amdgcn_mfma_f32_16x16x32_bf16(af.v, wf1[s][2], a10, 0, 0, 0);
                a11 = __builtin_amdgcn_mfma_f32_16x16x32_bf16(af.v, wf1[s][3], a11, 0, 0, 0);
            }
            // pool x-pairs in-lane, y-pair across lane c <-> c+8 (DPP, no LDS)
            f32x4 pe2, po2;
#pragma unroll
            for (int i = 0; i < 4; i++) {
                pe2[i] = fmax_x8(fmaxf(a00[i], a01[i]));
                po2[i] = fmax_x8(fmaxf(a10[i], a11[i]));
            }
            if (c < 6) {
#pragma unroll
                for (int i = 0; i < 4; i++) {
                    int m = grp * 4 + i;           // D row: sample = m>>3, quad = m&7
                    int qo = m & 7;
                    if (qo < 7) {
                        int sm = m >> 3;
                        float v0 = fmaxf(pe2[i] + bias1, 0.f);
                        float v1 = fmaxf(po2[i] + bias1, 0.f);
                        *(unsigned*)&p1s[(2 * st + sm) * P1R + (c * 14 + py) * 14 + qo * 2]
                            = cvtpk(v0, v1);
                    }
                }
            }
        }
        __syncthreads();   // img reads done before next convert; p1s subtile written
    }

    // ---- conv2 phase (wf2 loaded after conv1 regs die) ----
    short8 wf2[8][2];
#pragma unroll
    for (int s = 0; s < 8; s++)
#pragma unroll
        for (int off = 0; off < 2; off++)
            wf2[s][off] = *(const short8*)&c2wf[(((s * 2 + off) * 4 + grp) * 16 + c) * 8];
    int ciB[8], kyB[8];
#pragma unroll
    for (int s = 0; s < 8; s++) {
        int b = s * 4 + grp; if (b > 29) b = 29;   // clamped dup has zero weights
        ciB[s] = b / 5; kyB[s] = b % 5;
    }
    const float bias2 = c2b[c];

    for (int item = w; item < 25; item += 4) {
        int py = item / 5, px = item % 5;
        f32x4 a00 = {0.f,0.f,0.f,0.f}, a01 = a00, a10 = a00, a11 = a00;
#pragma unroll
        for (int s = 0; s < 8; s++) {
            int rbase = ciB[s] * 14 + kyB[s] + py * 2;
#pragma unroll
            for (int yo = 0; yo < 2; yo++) {
                int e = c * P1R + (rbase + yo) * 14 + px * 2;
                union { unsigned u[4]; short8 v; } af;
                af.u[0] = *(const unsigned*)&p1s[e];
                af.u[1] = *(const unsigned*)&p1s[e + 2];
                af.u[2] = *(const unsigned*)&p1s[e + 4];
                af.u[3] = *(const unsigned*)&p1s[e + 6];
                if (yo == 0) {
                    a00 = __builtin_amdgcn_mfma_f32_16x16x32_bf16(af.v, wf2[s][0], a00, 0, 0, 0);
                    a01 = __builtin_amdgcn_mfma_f32_16x16x32_bf16(af.v, wf2[s][1], a01, 0, 0, 0);
                } else {
                    a10 = __builtin_amdgcn_mfma_f32_16x16x32_bf16(af.v, wf2[s][0], a10, 0, 0, 0);
                    a11 = __builtin_amdgcn_mfma_f32_16x16x32_bf16(af.v, wf2[s][1], a11, 0, 0, 0);
                }
            }
        }
#pragma unroll
        for (int i = 0; i < 4; i++) {
            float mx = fmaxf(fmaxf(a00[i], a01[i]), fmaxf(a10[i], a11[i]));
            float v = fmaxf(mx + bias2, 0.f);
            int n = blockIdx.x * 16 + grp * 4 + i;
            P2[(size_t)n * 400 + c * 25 + py * 5 + px] = f2bf1(v);
        }
    }
}

// one-shot conversion: FC weights to padded bf16 tiles + conv weight fragments
__global__ __launch_bounds__(256) void prep_weights(
    const float* __restrict__ c1w, const float* __restrict__ c2w,
    const float* __restrict__ f1w, const float* __restrict__ f2w,
    const float* __restrict__ f3w,
    unsigned short* __restrict__ wb1, unsigned short* __restrict__ wb2,
    unsigned short* __restrict__ wb3,
    unsigned short* __restrict__ c1wf, unsigned short* __restrict__ c2wf)
{
    const int t0 = blockIdx.x * 256 + threadIdx.x;
    const int stride = gridDim.x * 256;
    for (int i = t0; i < 128 * 416; i += stride) {
        int o = i / 416, k = i % 416;
        wb1[i] = f2bf((o < 120 && k < 400) ? f1w[o * 400 + k] : 0.f);
    }
    for (int i = t0; i < 96 * 128; i += stride) {
        int o = i / 128, k = i % 128;
        wb2[i] = f2bf((o < 84 && k < 120) ? f2w[o * 120 + k] : 0.f);
    }
    for (int i = t0; i < 64 * 96; i += stride) {
        int o = i / 96, k = i % 96;
        wb3[i] = f2bf((k < 84) ? f3w[o * 84 + k] : 0.f);
    }
    // c1wf[s(5)][off(4)][grp(4)][c(16)][j(8)]
    for (int i = t0; i < 10240; i += stride) {
        int j = i & 7, c = (i >> 3) & 15, grp = (i >> 7) & 3;
        int off = (i >> 9) & 3, s = i >> 11;
        int b = s * 4 + grp;
        int ci = b / 6, kp = b % 6;
        int kx = j - off;
        float v = 0.f;
        if (b < 18 && kx >= 0 && kx <= 4) {
            if (c < 6 && kp <= 4)
                v = c1w[c * 75 + ci * 25 + kp * 5 + kx];
            else if (c >= 8 && c < 14 && kp >= 1)
                v = c1w[(c - 8) * 75 + ci * 25 + (kp - 1) * 5 + kx];
        }
        c1wf[i] = f2bf(v);
    }
    // c2wf[s(8)][off(2)][grp(4)][c(16)][j(8)]
    for (int i = t0; i < 8192; i += stride) {
        int j = i & 7, c = (i >> 3) & 15, grp = (i >> 7) & 3;
        int off = (i >> 9) & 1, s = i >> 10;
        int b = s * 4 + grp;
        int kx = j - off;
        float v = 0.f;
        if (b < 30 && kx >= 0 && kx <= 4) {
            int ci = b / 5, ky = b % 5;
            v = c2w[c * 150 + ci * 25 + ky * 5 + kx];
        }
        c2wf[i] = f2bf(v);
    }
}

#define FCS 32
#define P2S 424
#define A1S 136
#define A2S 104

// FC1->FC2->FC3 via bf16 MFMA + fused per-block embedding partial sum
__global__ __launch_bounds__(256, 3) void fc_mfma(
    const unsigned short* __restrict__ P2,
    const unsigned short* __restrict__ wb1, const float* __restrict__ f1b,
    const unsigned short* __restrict__ wb2, const float* __restrict__ f2b,
    const unsigned short* __restrict__ wb3, const float* __restrict__ f3b,
    float* __restrict__ emb, float* __restrict__ part)
{
    __shared__ __align__(16) unsigned short p2s[FCS * P2S];
    __shared__ __align__(16) unsigned short a1s[FCS * A1S];
    __shared__ __align__(16) unsigned short a2s[FCS * A2S];
    __shared__ float rsum[4];
    const int t = threadIdx.x, lane = t & 63, w = t >> 6;
    const int grp = lane >> 4, c = lane & 15;

    if (t < 64) {
        int s = t >> 1, h = t & 1;
        *(uint4*)&p2s[s * P2S + 400 + h * 8] = make_uint4(0u, 0u, 0u, 0u);
    }
    const uint4* src = (const uint4*)(P2 + (size_t)blockIdx.x * FCS * 400);
    for (int i = t; i < FCS * 50; i += 256) {
        int s = i / 50, k8 = i % 50;
        *(uint4*)&p2s[s * P2S + k8 * 8] = src[i];
    }
    __syncthreads();

    const int m = w & 1;
    const int arow = m * 16 + c;

    {
        const int n0 = (w >> 1) * 4;
        f32x4 acc[4] = {{0.f,0.f,0.f,0.f},{0.f,0.f,0.f,0.f},{0.f,0.f,0.f,0.f},{0.f,0.f,0.f,0.f}};
        const int sb = arow * P2S;
#pragma unroll
        for (int ks = 0; ks < 13; ks++) {
            short8 a = *(const short8*)&p2s[sb + ks * 32 + grp * 8];
#pragma unroll
            for (int j = 0; j < 4; j++) {
                int o = (n0 + j) * 16 + c;
                short8 b = *(const short8*)&wb1[o * 416 + ks * 32 + grp * 8];
                acc[j] = __builtin_amdgcn_mfma_f32_16x16x32_bf16(a, b, acc[j], 0, 0, 0);
            }
        }
#pragma unroll
        for (int j = 0; j < 4; j++) {
            int o = (n0 + j) * 16 + c;
            float bias = (o < 120) ? f1b[o] : 0.f;
#pragma unroll
            for (int i = 0; i < 4; i++) {
                int s = m * 16 + grp * 4 + i;
                a1s[s * A1S + o] = f2bf1(fmaxf(acc[j][i] + bias, 0.f));
            }
        }
    }
    __syncthreads();

    {
        const int n0 = (w >> 1) * 3;
        f32x4 acc[3] = {{0.f,0.f,0.f,0.f},{0.f,0.f,0.f,0.f},{0.f,0.f,0.f,0.f}};
        const int sb = arow * A1S;
#pragma unroll
        for (int ks = 0; ks < 4; ks++) {
            short8 a = *(const short8*)&a1s[sb + ks * 32 + grp * 8];
#pragma unroll
            for (int j = 0; j < 3; j++) {
                int o = (n0 + j) * 16 + c;
                short8 b = *(const short8*)&wb2[o * 128 + ks * 32 + grp * 8];
                acc[j] = __builtin_amdgcn_mfma_f32_16x16x32_bf16(a, b, acc[j], 0, 0, 0);
            }
        }
#pragma unroll
        for (int j = 0; j < 3; j++) {
            int o = (n0 + j) * 16 + c;
            float bias = (o < 84) ? f2b[o] : 0.f;
#pragma unroll
            for (int i = 0; i < 4; i++) {
                int s = m * 16 + grp * 4 + i;
                a2s[s * A2S + o] = f2bf1(fmaxf(acc[j][i] + bias, 0.f));
            }
        }
    }
    __syncthreads();

    {
        const int n0 = (w >> 1) * 2;
        f32x4 acc[2] = {{0.f,0.f,0.f,0.f},{0.f,0.f,0.f,0.f}};
        const int sb = arow * A2S;
#pragma unroll
        for (int ks = 0; ks < 3; ks++) {
            short8 a = *(const short8*)&a2s[sb + ks * 32 + grp * 8];
#pragma unroll
            for (int j = 0; j < 2; j++) {
                int o = (n0 + j) * 16 + c;
                short8 b = *(const short8*)&wb3[o * 96 + ks * 32 + grp * 8];
                acc[j] = __builtin_amdgcn_mfma_f32_16x16x32_bf16(a, b, acc[j], 0, 0, 0);
            }
        }
        float psum = 0.f;
#pragma unroll
        for (int j = 0; j < 2; j++) {
            int o = (n0 + j) * 16 + c;
            float bias = f3b[o];
#pragma unroll
            for (int i = 0; i < 4; i++) {
                int s = m * 16 + grp * 4 + i;
                float v = acc[j][i] + bias;
                emb[((size_t)blockIdx.x * FCS + s) * 64 + o] = v;
                psum += v;
            }
        }
        // fused deterministic per-block partial sum (replaces reduce_emb)
#pragma unroll
        for (int off = 32; off; off >>= 1) psum += __shfl_xor(psum, off);
        if (lane == 0) rsum[w] = psum;
        __syncthreads();
        if (t == 0) part[blockIdx.x] = (rsum[0] + rsum[1]) + (rsum[2] + rsum[3]);
    }
}

// 640 partials -> proto = sum / NUM_CLASSES (deterministic fixed-order)
__global__ __launch_bounds__(256) void reduce_part(const float* __restrict__ part,
                                                   float* __restrict__ proto) {
    __shared__ float s_[256];
    const int t = threadIdx.x;
    float s = part[t];
    if (t + 256 < 640) s += part[t + 256];
    if (t + 512 < 640) s += part[t + 512];
    s_[t] = s; __syncthreads();
    for (int off = 128; off > 0; off >>= 1) {
        if (t < off) s_[t] += s_[t + off];
        __syncthreads();
    }
    if (t == 0) proto[0] = s_[0] / 5.0f;
}

__global__ __launch_bounds__(256) void softmax_abs(float* __restrict__ io,
                                                   const float* __restrict__ proto_p) {
    const int lane = threadIdx.x & 63;
    const int row = (blockIdx.x << 2) + (threadIdx.x >> 6);
    const float proto = proto_p[0];
    float e = io[(size_t)row * 64 + lane];
    float m = e;
#pragma unroll
    for (int off = 32; off; off >>= 1) m = fmaxf(m, __shfl_xor(m, off));
    float p = expf(e - m);
    float s = p;
#pragma unroll
    for (int off = 32; off; off >>= 1) s += __shfl_xor(s, off);
    io[(size_t)row * 64 + lane] = fabsf(p / s - proto);
}

extern "C" void kernel_launch(void* const* d_in, const int* in_sizes, int n_in,
                              void* d_out, int out_size, void* d_ws, size_t ws_size,
                              hipStream_t stream) {
    const float* x   = (const float*)d_in[0];
    const float* c1w = (const float*)d_in[1];
    const float* c1b = (const float*)d_in[2];
    const float* c2w = (const float*)d_in[3];
    const float* c2b = (const float*)d_in[4];
    const float* f1w = (const float*)d_in[5];
    const float* f1b = (const float*)d_in[6];
    const float* f2w = (const float*)d_in[7];
    const float* f2b = (const float*)d_in[8];
    const float* f3w = (const float*)d_in[9];
    const float* f3b = (const float*)d_in[10];
    float* out = (float*)d_out;

    const int N = in_sizes[0] / 3072;                 // 20480
    const size_t p2_bytes = (size_t)N * 400 * 2;      // 16.4 MB
    unsigned short* P2 = (unsigned short*)d_ws;
    char* tail = (char*)d_ws + p2_bytes;
    float* part  = (float*)tail;                      // 640 floats
    float* proto = part + 640;                        // 1 float
    unsigned short* wb1  = (unsigned short*)(tail + 4096);  // 128x416
    unsigned short* wb2  = wb1 + 128 * 416;                 // 96x128
    unsigned short* wb3  = wb2 + 96 * 128;                  // 64x96
    unsigned short* c1wf = wb3 + 64 * 96;                   // 10240
    unsigned short* c2wf = c1wf + 10240;                    // 8192

    prep_weights<<<64, 256, 0, stream>>>(c1w, c2w, f1w, f2w, f3w,
                                         wb1, wb2, wb3, c1wf, c2wf);
    conv12_mfma<<<N / 16, 256, 0, stream>>>(x, c1wf, c1b, c2wf, c2b, P2);
    fc_mfma<<<N / 32, 256, 0, stream>>>(P2, wb1, f1b, wb2, f2b, wb3, f3b, out, part);
    reduce_part<<<1, 256, 0, stream>>>(part, proto);
    softmax_abs<<<N / 4, 256, 0, stream>>>(out, proto);
}